// Round 8
// baseline (553.347 us; speedup 1.0000x reference)
//
#include <hip/hip_runtime.h>
#include <hip/hip_bf16.h>

// B=4, H=W=64 -> N=4096, C=256, d=32
// All MFMA operands stored FRAGMENT-ORDERED so every load is a coalesced
// 1KB wave-load (lane-contiguous base + l*8 shorts).
//
// qF/kF [b][i>>5][f][lane][8] : lane = (i&31)+32*((d>>3)&1), f = d>>4, e = d&7
// vF    [b][i>>4][c>>5][lane][8] : lane = (c&31)+32*((i>>3)&1), e = i&7
// wallF [nf][ks][lane][8] : 16x16x32 B-frags of packed W^T (q|k|v)
// K (and bk) are pre-scaled by log2(e) so softmax uses v_exp_f32 (2^x) directly.
//
// ws layout (bytes):
//   qF    @ 0          1 MB
//   kF    @ 1 MB       1 MB
//   vF    @ 2 MB       8 MB
//   wallF @ 10 MB      160 KB
//   ball  @ +163840    1.25 KB
//   zpart @ +1280      512 KB   [8][16384] f32
//   rz    @ +524288    64 KB

typedef __attribute__((ext_vector_type(4)))  float    f32x4;
typedef __attribute__((ext_vector_type(16))) float    f32x16;
typedef __attribute__((ext_vector_type(8)))  short    bf8;
typedef __attribute__((ext_vector_type(4)))  short    bf4;
typedef __attribute__((ext_vector_type(4)))  unsigned u32x4;

__device__ __forceinline__ short f2bf(float f) {
    unsigned u = __builtin_bit_cast(unsigned, f);
    u += 0x7FFF + ((u >> 16) & 1);           // RNE
    return (short)(u >> 16);
}
__device__ __forceinline__ float bf2f(short h) {
    unsigned u = ((unsigned)(unsigned short)h) << 16;
    return __builtin_bit_cast(float, u);
}
__device__ __forceinline__ unsigned cvtpk(float lo, float hi) {
    unsigned r;
    asm("v_cvt_pk_bf16_f32 %0, %1, %2" : "=v"(r) : "v"(lo), "v"(hi));
    return r;
}
__device__ __forceinline__ float exp2_fast(float x) {   // 2^x, one v_exp_f32
    float r;
    asm("v_exp_f32 %0, %1" : "=v"(r) : "v"(x));
    return r;
}
__device__ __forceinline__ f32x16 z16() {
    f32x16 v;
#pragma unroll
    for (int i = 0; i < 16; ++i) v[i] = 0.f;
    return v;
}

#define LOG2E 1.44269504088896340736f

// ---------------- K1: pack weights into 16x16x32 B-frag order ---------------
__global__ __launch_bounds__(256) void pack_weights(
    const float* __restrict__ Wq, const float* __restrict__ Wk,
    const float* __restrict__ Wv, const float* __restrict__ bq,
    const float* __restrict__ bk, const float* __restrict__ bv,
    short* __restrict__ wallF, float* __restrict__ ball)
{
    int n = blockIdx.x;        // 0..319
    int k = threadIdx.x;       // 0..255
    float w;
    if (n < 32)       w = Wq[k * 32 + n];
    else if (n < 64)  w = Wk[k * 32 + (n - 32)] * LOG2E;   // fold log2e into K
    else              w = Wv[k * 256 + (n - 64)];
    int nf = n >> 4, lcol = n & 15;
    int ks = k >> 5, lg = (k >> 3) & 3, e = k & 7;
    wallF[((size_t)(nf * 8 + ks) * 64 + lg * 16 + lcol) * 8 + e] = f2bf(w);
    if (k == 0) {
        float bias = (n < 32) ? bq[n] : (n < 64) ? bk[n - 32] * LOG2E : bv[n - 64];
        ball[n] = bias;
    }
}

// ---------------- K2: QKV projection -> fragment-ordered qF/kF/vF -----------
// Grid 1024 (m16 per block), 4 waves split nf 20 -> 5 each. x rows L1-shared.
__global__ __launch_bounds__(256) void qkv_gemm(
    const float* __restrict__ x, const short* __restrict__ wallF,
    const float* __restrict__ ball,
    short* __restrict__ qf, short* __restrict__ kf, short* __restrict__ vf)
{
    const int w  = threadIdx.x >> 6;
    const int l  = threadIdx.x & 63;
    const int lr = l & 15;             // A row / B col within fragment
    const int lg = l >> 4;             // k-group
    const int m0 = blockIdx.x * 16;

    f32x4 acc[5];
#pragma unroll
    for (int i = 0; i < 5; ++i) acc[i] = (f32x4){0.f, 0.f, 0.f, 0.f};

    const float* xrow = x + (size_t)(m0 + lr) * 256 + lg * 8;
    const short* wwb  = wallF + (size_t)w * 5 * 4096 + l * 8;

#pragma unroll
    for (int ks = 0; ks < 8; ++ks) {
        f32x4 a0 = *(const f32x4*)(xrow + ks * 32);
        f32x4 a1 = *(const f32x4*)(xrow + ks * 32 + 4);
        bf8 af;
#pragma unroll
        for (int t = 0; t < 4; ++t) { af[t] = f2bf(a0[t]); af[t + 4] = f2bf(a1[t]); }
        const short* wb = wwb + (size_t)ks * 512;
#pragma unroll
        for (int nf2 = 0; nf2 < 5; ++nf2) {
            bf8 bfr = *(const bf8*)(wb + (size_t)nf2 * 4096);
            acc[nf2] = __builtin_amdgcn_mfma_f32_16x16x32_bf16(af, bfr, acc[nf2], 0, 0, 0);
        }
    }

    const int b      = m0 >> 12;
    const int i_base = m0 + lg * 4;          // rows i_base..i_base+3
#pragma unroll
    for (int nf2 = 0; nf2 < 5; ++nf2) {
        int nf = w * 5 + nf2;
        int n = nf * 16 + lr;
        float bias = ball[n];
        if (nf < 4) {          // q (nf<2) / k: d = n & 31
            int d = n & 31;
            int f = (d >> 4) & 1, sub = (d >> 3) & 1, e = d & 7;
            short* dst = (nf < 2) ? qf : kf;
            size_t base = ((size_t)(b * 128 + (i_base >> 5)) * 2 + f) * 512 + 256 * sub + e;
#pragma unroll
            for (int r = 0; r < 4; ++r) {
                int i31 = (i_base + r) & 31;
                dst[base + (size_t)i31 * 8] = f2bf(acc[nf2][r] + bias);
            }
        } else {               // v: c = n - 64
            int c = n - 64;
            bf4 pv;
#pragma unroll
            for (int r = 0; r < 4; ++r) pv[r] = f2bf(acc[nf2][r] + bias);
            size_t addr = (size_t)(b * 256 + (i_base >> 4)) * 4096
                        + (size_t)(c >> 5) * 512
                        + (size_t)((c & 31) + 32 * ((i_base >> 3) & 1)) * 8
                        + (i_base & 7);
            *(bf4*)(vf + addr) = pv;
        }
    }
}

// ---------------- K3: Z_i = sum_j 2^(q_i . k_j), swapped operands ------------
// 8 waves split j into 512-chunks; i on lanes, j on regs -> j-reduce in-lane.
__global__ __launch_bounds__(512) void zsum_kernel(
    const short* __restrict__ qF, const short* __restrict__ kF,
    float* __restrict__ zpart)
{
    const int l = threadIdx.x & 63, w = threadIdx.x >> 6;
    const int b = blockIdx.y;
    const int itile = blockIdx.x;            // 0..127

    const short* qp = qF + (size_t)(b * 128 + itile) * 1024 + l * 8;
    bf8 qb0 = *(const bf8*)(qp);
    bf8 qb1 = *(const bf8*)(qp + 512);

    float zacc = 0.f;
    const short* kbase = kF + (size_t)b * 131072 + (size_t)w * 16384 + l * 8;
    for (int jt = 0; jt < 16; ++jt) {
        const short* kp = kbase + jt * 1024;
        bf8 kA0 = *(const bf8*)(kp);
        bf8 kA1 = *(const bf8*)(kp + 512);
        f32x16 S = z16();
        S = __builtin_amdgcn_mfma_f32_32x32x16_bf16(kA0, qb0, S, 0, 0, 0);
        S = __builtin_amdgcn_mfma_f32_32x32x16_bf16(kA1, qb1, S, 0, 0, 0);
#pragma unroll
        for (int r = 0; r < 16; ++r) zacc += exp2_fast(fminf(S[r], 86.f));
    }
    zacc += __shfl_xor(zacc, 32);
    if (l < 32)
        zpart[(size_t)w * 16384 + b * 4096 + itile * 32 + l] = zacc;
}

// ---------------- K3b: rz = 1 / sum(partials) --------------------------------
__global__ __launch_bounds__(256) void zfinish(
    const float* __restrict__ zpart, float* __restrict__ rz)
{
    int i = blockIdx.x * 256 + threadIdx.x;   // 0..16383
    float z = 0.f;
#pragma unroll
    for (int p = 0; p < 8; ++p) z += zpart[p * 16384 + i];
    rz[i] = 1.0f / z;
}

// ---------------- K4: vs = v / Z  (in place on vF) ---------------------------
__global__ __launch_bounds__(256) void vscale(
    short* __restrict__ vF, const float* __restrict__ rz)
{
    int t = blockIdx.x * 256 + threadIdx.x;      // 0..524287
    size_t base = (size_t)t * 8;
    int b   = (int)(base >> 20);
    int rem = (int)(base & 1048575);
    int it  = rem >> 12;
    int sub = (rem >> 8) & 1;                    // lane>>5
    int i0  = it * 16 + sub * 8;
    bf8 v = *(bf8*)(vF + base);
    const float* rzp = rz + b * 4096 + i0;
    f32x4 r0 = *(const f32x4*)(rzp);
    f32x4 r1 = *(const f32x4*)(rzp + 4);
#pragma unroll
    for (int e = 0; e < 4; ++e) {
        v[e]     = f2bf(bf2f(v[e])     * r0[e]);
        v[e + 4] = f2bf(bf2f(v[e + 4]) * r1[e]);
    }
    *(bf8*)(vF + base) = v;
}

// ---------------- K5: out = gamma * (P^T @ vs) + x ---------------------------
// Grid 256 = 8 XCD x 32: XCD x -> (b = x>>1, ch = x&1), 32 j-tiles of 128.
// Block 1024 = 16 waves = (4 wj) x (4 i-quarters); ALL 16 waves co-resident
// on one CU -> guaranteed 4 waves/SIMD. NO min-waves register cap (R6 lesson:
// the cap forced VGPR=64 < live state and spilled 1.5 GB to scratch).
// Wave: j32 x c128, 32 i-steps; softmax in-register; 1/Z folded into vs.
// Epilogue: 3-round LDS reduce across the 4 i-quarter waves.
__global__ __launch_bounds__(1024) void attn_out(
    const short* __restrict__ qF, const short* __restrict__ kF,
    const short* __restrict__ vF,
    const float* __restrict__ x, const float* __restrict__ gammaPtr,
    float* __restrict__ out)
{
    __shared__ float red[4][32][128];            // 64 KB, epilogue only
    const int l = threadIdx.x & 63, w = threadIdx.x >> 6;
    const int lr = l & 31, hi = l >> 5;
    const int wj = w & 3, isub = w >> 2;

    const int xcd = blockIdx.x & 7, jt = blockIdx.x >> 3;   // jt 0..31
    const int b = xcd >> 1, ch = xcd & 1;
    const int j0 = jt * 128;
    const int c0 = ch * 128;

    const short* kfp = kF + (size_t)(b * 128 + jt * 4 + wj) * 1024 + l * 8;
    bf8 kf0 = *(const bf8*)(kfp);
    bf8 kf1 = *(const bf8*)(kfp + 512);

    f32x16 acc[4];
#pragma unroll
    for (int cf = 0; cf < 4; ++cf) acc[cf] = z16();

    const short* qbase = qF + (size_t)b * 131072 + (size_t)isub * 32768 + l * 8;
    const short* vbase = vF + (size_t)b * 1048576 + (size_t)isub * 262144
                       + (size_t)(c0 >> 5) * 512 + l * 8;

    // preload t=0
    bf8 q0 = *(const bf8*)(qbase);
    bf8 q1 = *(const bf8*)(qbase + 512);
    bf8 v0[4], v1[4];
#pragma unroll
    for (int cf = 0; cf < 4; ++cf) {
        v0[cf] = *(const bf8*)(vbase + cf * 512);
        v1[cf] = *(const bf8*)(vbase + 4096 + cf * 512);
    }

    for (int t = 0; t < 32; ++t) {
        bf8 nq0, nq1, nv0[4], nv1[4];
        if (t < 31) {
            const short* qn = qbase + (t + 1) * 1024;
            nq0 = *(const bf8*)(qn);
            nq1 = *(const bf8*)(qn + 512);
            const short* vn = vbase + (size_t)(t + 1) * 8192;
#pragma unroll
            for (int cf = 0; cf < 4; ++cf) {
                nv0[cf] = *(const bf8*)(vn + cf * 512);
                nv1[cf] = *(const bf8*)(vn + 4096 + cf * 512);
            }
        }

        f32x16 S = z16();
        S = __builtin_amdgcn_mfma_f32_32x32x16_bf16(q0, kf0, S, 0, 0, 0);
        S = __builtin_amdgcn_mfma_f32_32x32x16_bf16(q1, kf1, S, 0, 0, 0);

        float p[16];
#pragma unroll
        for (int r = 0; r < 16; ++r) p[r] = exp2_fast(fminf(S[r], 86.f));

        unsigned X0 = cvtpk(p[0],  p[1]),  Y0 = cvtpk(p[4],  p[5]);
        unsigned X1 = cvtpk(p[2],  p[3]),  Y1 = cvtpk(p[6],  p[7]);
        unsigned X2 = cvtpk(p[8],  p[9]),  Y2 = cvtpk(p[12], p[13]);
        unsigned X3 = cvtpk(p[10], p[11]), Y3 = cvtpk(p[14], p[15]);
        asm("v_permlane32_swap_b32 %0, %1" : "+v"(X0), "+v"(Y0));
        asm("v_permlane32_swap_b32 %0, %1" : "+v"(X1), "+v"(Y1));
        asm("v_permlane32_swap_b32 %0, %1" : "+v"(X2), "+v"(Y2));
        asm("v_permlane32_swap_b32 %0, %1" : "+v"(X3), "+v"(Y3));
        u32x4 a0w = {X0, X1, Y0, Y1};
        u32x4 a1w = {X2, X3, Y2, Y3};
        bf8 A0 = __builtin_bit_cast(bf8, a0w);
        bf8 A1 = __builtin_bit_cast(bf8, a1w);

        __builtin_amdgcn_s_setprio(1);
#pragma unroll
        for (int cf = 0; cf < 4; ++cf) {
            acc[cf] = __builtin_amdgcn_mfma_f32_32x32x16_bf16(A0, v0[cf], acc[cf], 0, 0, 0);
            acc[cf] = __builtin_amdgcn_mfma_f32_32x32x16_bf16(A1, v1[cf], acc[cf], 0, 0, 0);
        }
        __builtin_amdgcn_s_setprio(0);

        q0 = nq0; q1 = nq1;
#pragma unroll
        for (int cf = 0; cf < 4; ++cf) { v0[cf] = nv0[cf]; v1[cf] = nv1[cf]; }
    }

    // epilogue: 3-round reduce of the 4 i-quarter partials into isub 0
#pragma unroll
    for (int src = 1; src < 4; ++src) {
        if (isub == src) {
#pragma unroll
            for (int cf = 0; cf < 4; ++cf)
#pragma unroll
                for (int r = 0; r < 16; ++r) {
                    int jrow = (r & 3) + 8 * (r >> 2) + 4 * hi;
                    red[wj][jrow][cf * 32 + lr] = acc[cf][r];
                }
        }
        __syncthreads();
        if (isub == 0) {
#pragma unroll
            for (int cf = 0; cf < 4; ++cf)
#pragma unroll
                for (int r = 0; r < 16; ++r) {
                    int jrow = (r & 3) + 8 * (r >> 2) + 4 * hi;
                    acc[cf][r] += red[wj][jrow][cf * 32 + lr];
                }
        }
        __syncthreads();
    }
    if (isub == 0) {
        const float gamma = *gammaPtr;
#pragma unroll
        for (int cf = 0; cf < 4; ++cf)
#pragma unroll
            for (int r = 0; r < 16; ++r) {
                int jrow = (r & 3) + 8 * (r >> 2) + 4 * hi;
                int j = j0 + wj * 32 + jrow;
                size_t idx = (size_t)(b * 4096 + j) * 256 + c0 + cf * 32 + lr;
                out[idx] = gamma * acc[cf][r] + x[idx];
            }
    }
}

extern "C" void kernel_launch(void* const* d_in, const int* in_sizes, int n_in,
                              void* d_out, int out_size, void* d_ws, size_t ws_size,
                              hipStream_t stream)
{
    const float* x  = (const float*)d_in[0];
    const float* Wq = (const float*)d_in[1];
    const float* bq = (const float*)d_in[2];
    const float* Wk = (const float*)d_in[3];
    const float* bk = (const float*)d_in[4];
    const float* Wv = (const float*)d_in[5];
    const float* bv = (const float*)d_in[6];
    const float* gm = (const float*)d_in[7];
    float* out = (float*)d_out;

    char* wsb = (char*)d_ws;
    short* qf    = (short*)(wsb);
    short* kf    = (short*)(wsb + (1u << 20));
    short* vf    = (short*)(wsb + (2u << 20));
    short* wallF = (short*)(wsb + (10u << 20));
    float* ball  = (float*)(wsb + (10u << 20) + 163840);
    float* zpart = (float*)(wsb + (10u << 20) + 163840 + 1280);
    float* rz    = (float*)(wsb + (10u << 20) + 163840 + 1280 + 524288);

    pack_weights<<<320, 256, 0, stream>>>(Wq, Wk, Wv, bq, bk, bv, wallF, ball);
    qkv_gemm<<<1024, 256, 0, stream>>>(x, wallF, ball, qf, kf, vf);
    zsum_kernel<<<dim3(128, 4), 512, 0, stream>>>(qf, kf, zpart);
    zfinish<<<64, 256, 0, stream>>>(zpart, rz);
    vscale<<<2048, 256, 0, stream>>>(vf, rz);
    attn_out<<<256, 1024, 0, stream>>>(qf, kf, vf, x, gm, out);
}

// Round 9
// 549.432 us; speedup vs baseline: 1.0071x; 1.0071x over previous
//
#include <hip/hip_runtime.h>
#include <hip/hip_bf16.h>

// B=4, H=W=64 -> N=4096, C=256, d=32
// All MFMA operands stored FRAGMENT-ORDERED so every load is a coalesced
// 1KB wave-load (lane-contiguous base + l*8 shorts).
//
// qF/kF [b][i>>5][f][lane][8] : lane = (i&31)+32*((d>>3)&1), f = d>>4, e = d&7
// vF    [b][i>>4][c>>5][lane][8] : lane = (c&31)+32*((i>>3)&1), e = i&7
// wallF [nf][ks][lane][8] : 16x16x32 B-frags of packed W^T (q|k|v)
// K (and bk) are pre-scaled by log2(e) so softmax uses v_exp_f32 (2^x) directly.
//
// ws layout (bytes):
//   qF    @ 0          1 MB
//   kF    @ 1 MB       1 MB
//   vF    @ 2 MB       8 MB
//   wallF @ 10 MB      160 KB
//   ball  @ +163840    1.25 KB
//   zpart @ +1280      512 KB   [8][16384] f32
//   rz    @ +524288    64 KB

typedef __attribute__((ext_vector_type(4)))  float    f32x4;
typedef __attribute__((ext_vector_type(16))) float    f32x16;
typedef __attribute__((ext_vector_type(8)))  short    bf8;
typedef __attribute__((ext_vector_type(4)))  short    bf4;
typedef __attribute__((ext_vector_type(4)))  unsigned u32x4;

__device__ __forceinline__ short f2bf(float f) {
    unsigned u = __builtin_bit_cast(unsigned, f);
    u += 0x7FFF + ((u >> 16) & 1);           // RNE
    return (short)(u >> 16);
}
__device__ __forceinline__ float bf2f(short h) {
    unsigned u = ((unsigned)(unsigned short)h) << 16;
    return __builtin_bit_cast(float, u);
}
__device__ __forceinline__ unsigned cvtpk(float lo, float hi) {
    unsigned r;
    asm("v_cvt_pk_bf16_f32 %0, %1, %2" : "=v"(r) : "v"(lo), "v"(hi));
    return r;
}
__device__ __forceinline__ float exp2_fast(float x) {   // 2^x, one v_exp_f32
    float r;
    asm("v_exp_f32 %0, %1" : "=v"(r) : "v"(x));
    return r;
}
__device__ __forceinline__ f32x16 z16() {
    f32x16 v;
#pragma unroll
    for (int i = 0; i < 16; ++i) v[i] = 0.f;
    return v;
}

#define LOG2E 1.44269504088896340736f

// ---------------- K1: pack weights into 16x16x32 B-frag order ---------------
__global__ __launch_bounds__(256) void pack_weights(
    const float* __restrict__ Wq, const float* __restrict__ Wk,
    const float* __restrict__ Wv, const float* __restrict__ bq,
    const float* __restrict__ bk, const float* __restrict__ bv,
    short* __restrict__ wallF, float* __restrict__ ball)
{
    int n = blockIdx.x;        // 0..319
    int k = threadIdx.x;       // 0..255
    float w;
    if (n < 32)       w = Wq[k * 32 + n];
    else if (n < 64)  w = Wk[k * 32 + (n - 32)] * LOG2E;   // fold log2e into K
    else              w = Wv[k * 256 + (n - 64)];
    int nf = n >> 4, lcol = n & 15;
    int ks = k >> 5, lg = (k >> 3) & 3, e = k & 7;
    wallF[((size_t)(nf * 8 + ks) * 64 + lg * 16 + lcol) * 8 + e] = f2bf(w);
    if (k == 0) {
        float bias = (n < 32) ? bq[n] : (n < 64) ? bk[n - 32] * LOG2E : bv[n - 64];
        ball[n] = bias;
    }
}

// ---------------- K2: QKV projection -> fragment-ordered qF/kF/vF -----------
// Grid 1024 (m16 per block), 4 waves split nf 20 -> 5 each. x rows L1-shared.
__global__ __launch_bounds__(256) void qkv_gemm(
    const float* __restrict__ x, const short* __restrict__ wallF,
    const float* __restrict__ ball,
    short* __restrict__ qf, short* __restrict__ kf, short* __restrict__ vf)
{
    const int w  = threadIdx.x >> 6;
    const int l  = threadIdx.x & 63;
    const int lr = l & 15;             // A row / B col within fragment
    const int lg = l >> 4;             // k-group
    const int m0 = blockIdx.x * 16;

    f32x4 acc[5];
#pragma unroll
    for (int i = 0; i < 5; ++i) acc[i] = (f32x4){0.f, 0.f, 0.f, 0.f};

    const float* xrow = x + (size_t)(m0 + lr) * 256 + lg * 8;
    const short* wwb  = wallF + (size_t)w * 5 * 4096 + l * 8;

#pragma unroll
    for (int ks = 0; ks < 8; ++ks) {
        f32x4 a0 = *(const f32x4*)(xrow + ks * 32);
        f32x4 a1 = *(const f32x4*)(xrow + ks * 32 + 4);
        bf8 af;
#pragma unroll
        for (int t = 0; t < 4; ++t) { af[t] = f2bf(a0[t]); af[t + 4] = f2bf(a1[t]); }
        const short* wb = wwb + (size_t)ks * 512;
#pragma unroll
        for (int nf2 = 0; nf2 < 5; ++nf2) {
            bf8 bfr = *(const bf8*)(wb + (size_t)nf2 * 4096);
            acc[nf2] = __builtin_amdgcn_mfma_f32_16x16x32_bf16(af, bfr, acc[nf2], 0, 0, 0);
        }
    }

    const int b      = m0 >> 12;
    const int i_base = m0 + lg * 4;          // rows i_base..i_base+3
#pragma unroll
    for (int nf2 = 0; nf2 < 5; ++nf2) {
        int nf = w * 5 + nf2;
        int n = nf * 16 + lr;
        float bias = ball[n];
        if (nf < 4) {          // q (nf<2) / k: d = n & 31
            int d = n & 31;
            int f = (d >> 4) & 1, sub = (d >> 3) & 1, e = d & 7;
            short* dst = (nf < 2) ? qf : kf;
            size_t base = ((size_t)(b * 128 + (i_base >> 5)) * 2 + f) * 512 + 256 * sub + e;
#pragma unroll
            for (int r = 0; r < 4; ++r) {
                int i31 = (i_base + r) & 31;
                dst[base + (size_t)i31 * 8] = f2bf(acc[nf2][r] + bias);
            }
        } else {               // v: c = n - 64
            int c = n - 64;
            bf4 pv;
#pragma unroll
            for (int r = 0; r < 4; ++r) pv[r] = f2bf(acc[nf2][r] + bias);
            size_t addr = (size_t)(b * 256 + (i_base >> 4)) * 4096
                        + (size_t)(c >> 5) * 512
                        + (size_t)((c & 31) + 32 * ((i_base >> 3) & 1)) * 8
                        + (i_base & 7);
            *(bf4*)(vf + addr) = pv;
        }
    }
}

// ---------------- K3: Z_i = sum_j 2^(q_i . k_j), swapped operands ------------
// 8 waves split j into 512-chunks; i on lanes, j on regs -> j-reduce in-lane.
__global__ __launch_bounds__(512) void zsum_kernel(
    const short* __restrict__ qF, const short* __restrict__ kF,
    float* __restrict__ zpart)
{
    const int l = threadIdx.x & 63, w = threadIdx.x >> 6;
    const int b = blockIdx.y;
    const int itile = blockIdx.x;            // 0..127

    const short* qp = qF + (size_t)(b * 128 + itile) * 1024 + l * 8;
    bf8 qb0 = *(const bf8*)(qp);
    bf8 qb1 = *(const bf8*)(qp + 512);

    float zacc = 0.f;
    const short* kbase = kF + (size_t)b * 131072 + (size_t)w * 16384 + l * 8;
    for (int jt = 0; jt < 16; ++jt) {
        const short* kp = kbase + jt * 1024;
        bf8 kA0 = *(const bf8*)(kp);
        bf8 kA1 = *(const bf8*)(kp + 512);
        f32x16 S = z16();
        S = __builtin_amdgcn_mfma_f32_32x32x16_bf16(kA0, qb0, S, 0, 0, 0);
        S = __builtin_amdgcn_mfma_f32_32x32x16_bf16(kA1, qb1, S, 0, 0, 0);
#pragma unroll
        for (int r = 0; r < 16; ++r) zacc += exp2_fast(fminf(S[r], 86.f));
    }
    zacc += __shfl_xor(zacc, 32);
    if (l < 32)
        zpart[(size_t)w * 16384 + b * 4096 + itile * 32 + l] = zacc;
}

// ---------------- K3b: rz = 1 / sum(partials) --------------------------------
__global__ __launch_bounds__(256) void zfinish(
    const float* __restrict__ zpart, float* __restrict__ rz)
{
    int i = blockIdx.x * 256 + threadIdx.x;   // 0..16383
    float z = 0.f;
#pragma unroll
    for (int p = 0; p < 8; ++p) z += zpart[p * 16384 + i];
    rz[i] = 1.0f / z;
}

// ---------------- K4: vs = v / Z  (in place on vF) ---------------------------
__global__ __launch_bounds__(256) void vscale(
    short* __restrict__ vF, const float* __restrict__ rz)
{
    int t = blockIdx.x * 256 + threadIdx.x;      // 0..524287
    size_t base = (size_t)t * 8;
    int b   = (int)(base >> 20);
    int rem = (int)(base & 1048575);
    int it  = rem >> 12;
    int sub = (rem >> 8) & 1;                    // lane>>5
    int i0  = it * 16 + sub * 8;
    bf8 v = *(bf8*)(vF + base);
    const float* rzp = rz + b * 4096 + i0;
    f32x4 r0 = *(const f32x4*)(rzp);
    f32x4 r1 = *(const f32x4*)(rzp + 4);
#pragma unroll
    for (int e = 0; e < 4; ++e) {
        v[e]     = f2bf(bf2f(v[e])     * r0[e]);
        v[e + 4] = f2bf(bf2f(v[e + 4]) * r1[e]);
    }
    *(bf8*)(vF + base) = v;
}

// ---------------- K5: out = gamma * (P^T @ vs) + x ---------------------------
// Grid 256 = 8 XCD x 32: XCD x -> (b = x>>1, ch = x&1), 32 j-tiles of 128.
// Block 1024 = 16 waves = (4 wj) x (4 i-quarters); ALL 16 waves co-resident
// on one CU -> guaranteed 4 waves/SIMD.
// __launch_bounds__(1024, 1): the ",1" is ESSENTIAL — without it the backend
// targets 8 waves/SIMD and caps VGPR at 64 < the ~88-reg live set, spilling
// 1.5 GB/launch to scratch (R6+R8 failure, 516 us). Hard cap from the
// 1024-thread block is 128 VGPR; the proven inner loop needs ~88.
// Wave: j32 x c128, 32 i-steps; softmax in-register; 1/Z folded into vs.
// Epilogue: 3-round LDS reduce across the 4 i-quarter waves.
__global__ __launch_bounds__(1024, 1) void attn_out(
    const short* __restrict__ qF, const short* __restrict__ kF,
    const short* __restrict__ vF,
    const float* __restrict__ x, const float* __restrict__ gammaPtr,
    float* __restrict__ out)
{
    __shared__ float red[4][32][128];            // 64 KB, epilogue only
    const int l = threadIdx.x & 63, w = threadIdx.x >> 6;
    const int lr = l & 31, hi = l >> 5;
    const int wj = w & 3, isub = w >> 2;

    const int xcd = blockIdx.x & 7, jt = blockIdx.x >> 3;   // jt 0..31
    const int b = xcd >> 1, ch = xcd & 1;
    const int j0 = jt * 128;
    const int c0 = ch * 128;

    const short* kfp = kF + (size_t)(b * 128 + jt * 4 + wj) * 1024 + l * 8;
    bf8 kf0 = *(const bf8*)(kfp);
    bf8 kf1 = *(const bf8*)(kfp + 512);

    f32x16 acc[4];
#pragma unroll
    for (int cf = 0; cf < 4; ++cf) acc[cf] = z16();

    const short* qbase = qF + (size_t)b * 131072 + (size_t)isub * 32768 + l * 8;
    const short* vbase = vF + (size_t)b * 1048576 + (size_t)isub * 262144
                       + (size_t)(c0 >> 5) * 512 + l * 8;

    // preload t=0
    bf8 q0 = *(const bf8*)(qbase);
    bf8 q1 = *(const bf8*)(qbase + 512);
    bf8 v0[4], v1[4];
#pragma unroll
    for (int cf = 0; cf < 4; ++cf) {
        v0[cf] = *(const bf8*)(vbase + cf * 512);
        v1[cf] = *(const bf8*)(vbase + 4096 + cf * 512);
    }

    for (int t = 0; t < 32; ++t) {
        bf8 nq0, nq1, nv0[4], nv1[4];
        if (t < 31) {
            const short* qn = qbase + (t + 1) * 1024;
            nq0 = *(const bf8*)(qn);
            nq1 = *(const bf8*)(qn + 512);
            const short* vn = vbase + (size_t)(t + 1) * 8192;
#pragma unroll
            for (int cf = 0; cf < 4; ++cf) {
                nv0[cf] = *(const bf8*)(vn + cf * 512);
                nv1[cf] = *(const bf8*)(vn + 4096 + cf * 512);
            }
        }

        f32x16 S = z16();
        S = __builtin_amdgcn_mfma_f32_32x32x16_bf16(q0, kf0, S, 0, 0, 0);
        S = __builtin_amdgcn_mfma_f32_32x32x16_bf16(q1, kf1, S, 0, 0, 0);

        float p[16];
#pragma unroll
        for (int r = 0; r < 16; ++r) p[r] = exp2_fast(fminf(S[r], 86.f));

        unsigned X0 = cvtpk(p[0],  p[1]),  Y0 = cvtpk(p[4],  p[5]);
        unsigned X1 = cvtpk(p[2],  p[3]),  Y1 = cvtpk(p[6],  p[7]);
        unsigned X2 = cvtpk(p[8],  p[9]),  Y2 = cvtpk(p[12], p[13]);
        unsigned X3 = cvtpk(p[10], p[11]), Y3 = cvtpk(p[14], p[15]);
        asm("v_permlane32_swap_b32 %0, %1" : "+v"(X0), "+v"(Y0));
        asm("v_permlane32_swap_b32 %0, %1" : "+v"(X1), "+v"(Y1));
        asm("v_permlane32_swap_b32 %0, %1" : "+v"(X2), "+v"(Y2));
        asm("v_permlane32_swap_b32 %0, %1" : "+v"(X3), "+v"(Y3));
        u32x4 a0w = {X0, X1, Y0, Y1};
        u32x4 a1w = {X2, X3, Y2, Y3};
        bf8 A0 = __builtin_bit_cast(bf8, a0w);
        bf8 A1 = __builtin_bit_cast(bf8, a1w);

        __builtin_amdgcn_s_setprio(1);
#pragma unroll
        for (int cf = 0; cf < 4; ++cf) {
            acc[cf] = __builtin_amdgcn_mfma_f32_32x32x16_bf16(A0, v0[cf], acc[cf], 0, 0, 0);
            acc[cf] = __builtin_amdgcn_mfma_f32_32x32x16_bf16(A1, v1[cf], acc[cf], 0, 0, 0);
        }
        __builtin_amdgcn_s_setprio(0);

        q0 = nq0; q1 = nq1;
#pragma unroll
        for (int cf = 0; cf < 4; ++cf) { v0[cf] = nv0[cf]; v1[cf] = nv1[cf]; }
    }

    // epilogue: 3-round reduce of the 4 i-quarter partials into isub 0
#pragma unroll
    for (int src = 1; src < 4; ++src) {
        if (isub == src) {
#pragma unroll
            for (int cf = 0; cf < 4; ++cf)
#pragma unroll
                for (int r = 0; r < 16; ++r) {
                    int jrow = (r & 3) + 8 * (r >> 2) + 4 * hi;
                    red[wj][jrow][cf * 32 + lr] = acc[cf][r];
                }
        }
        __syncthreads();
        if (isub == 0) {
#pragma unroll
            for (int cf = 0; cf < 4; ++cf)
#pragma unroll
                for (int r = 0; r < 16; ++r) {
                    int jrow = (r & 3) + 8 * (r >> 2) + 4 * hi;
                    acc[cf][r] += red[wj][jrow][cf * 32 + lr];
                }
        }
        __syncthreads();
    }
    if (isub == 0) {
        const float gamma = *gammaPtr;
#pragma unroll
        for (int cf = 0; cf < 4; ++cf)
#pragma unroll
            for (int r = 0; r < 16; ++r) {
                int jrow = (r & 3) + 8 * (r >> 2) + 4 * hi;
                int j = j0 + wj * 32 + jrow;
                size_t idx = (size_t)(b * 4096 + j) * 256 + c0 + cf * 32 + lr;
                out[idx] = gamma * acc[cf][r] + x[idx];
            }
    }
}

extern "C" void kernel_launch(void* const* d_in, const int* in_sizes, int n_in,
                              void* d_out, int out_size, void* d_ws, size_t ws_size,
                              hipStream_t stream)
{
    const float* x  = (const float*)d_in[0];
    const float* Wq = (const float*)d_in[1];
    const float* bq = (const float*)d_in[2];
    const float* Wk = (const float*)d_in[3];
    const float* bk = (const float*)d_in[4];
    const float* Wv = (const float*)d_in[5];
    const float* bv = (const float*)d_in[6];
    const float* gm = (const float*)d_in[7];
    float* out = (float*)d_out;

    char* wsb = (char*)d_ws;
    short* qf    = (short*)(wsb);
    short* kf    = (short*)(wsb + (1u << 20));
    short* vf    = (short*)(wsb + (2u << 20));
    short* wallF = (short*)(wsb + (10u << 20));
    float* ball  = (float*)(wsb + (10u << 20) + 163840);
    float* zpart = (float*)(wsb + (10u << 20) + 163840 + 1280);
    float* rz    = (float*)(wsb + (10u << 20) + 163840 + 1280 + 524288);

    pack_weights<<<320, 256, 0, stream>>>(Wq, Wk, Wv, bq, bk, bv, wallF, ball);
    qkv_gemm<<<1024, 256, 0, stream>>>(x, wallF, ball, qf, kf, vf);
    zsum_kernel<<<dim3(128, 4), 512, 0, stream>>>(qf, kf, zpart);
    zfinish<<<64, 256, 0, stream>>>(zpart, rz);
    vscale<<<2048, 256, 0, stream>>>(vf, rz);
    attn_out<<<256, 1024, 0, stream>>>(qf, kf, vf, x, gm, out);
}

// Round 10
// 113.774 us; speedup vs baseline: 4.8636x; 4.8291x over previous
//
#include <hip/hip_runtime.h>
#include <hip/hip_bf16.h>

// B=4, H=W=64 -> N=4096, C=256, d=32
// All MFMA operands stored FRAGMENT-ORDERED so every load is a coalesced
// 1KB wave-load (lane-contiguous base + l*8 shorts).
//
// qF/kF [b][i>>5][f][lane][8] : lane = (i&31)+32*((d>>3)&1), f = d>>4, e = d&7
// vF    [b][i>>4][c>>5][lane][8] : lane = (c&31)+32*((i>>3)&1), e = i&7
// wallF [nf][ks][lane][8] : 16x16x32 B-frags of packed W^T (q|k|v)
// K (and bk) are pre-scaled by log2(e) so softmax uses v_exp_f32 (2^x) directly.
//
// ws layout (bytes):
//   qF    @ 0          1 MB
//   kF    @ 1 MB       1 MB
//   vF    @ 2 MB       8 MB
//   wallF @ 10 MB      160 KB
//   ball  @ +163840    1.25 KB
//   zpart @ +1280      512 KB   [8][16384] f32
//   rz    @ +524288    64 KB

typedef __attribute__((ext_vector_type(4)))  float    f32x4;
typedef __attribute__((ext_vector_type(16))) float    f32x16;
typedef __attribute__((ext_vector_type(8)))  short    bf8;
typedef __attribute__((ext_vector_type(4)))  short    bf4;
typedef __attribute__((ext_vector_type(4)))  unsigned u32x4;

__device__ __forceinline__ short f2bf(float f) {
    unsigned u = __builtin_bit_cast(unsigned, f);
    u += 0x7FFF + ((u >> 16) & 1);           // RNE
    return (short)(u >> 16);
}
__device__ __forceinline__ float bf2f(short h) {
    unsigned u = ((unsigned)(unsigned short)h) << 16;
    return __builtin_bit_cast(float, u);
}
__device__ __forceinline__ unsigned cvtpk(float lo, float hi) {
    unsigned r;
    asm("v_cvt_pk_bf16_f32 %0, %1, %2" : "=v"(r) : "v"(lo), "v"(hi));
    return r;
}
__device__ __forceinline__ float exp2_fast(float x) {   // 2^x, one v_exp_f32
    float r;
    asm("v_exp_f32 %0, %1" : "=v"(r) : "v"(x));
    return r;
}
__device__ __forceinline__ f32x16 z16() {
    f32x16 v;
#pragma unroll
    for (int i = 0; i < 16; ++i) v[i] = 0.f;
    return v;
}

#define LOG2E 1.44269504088896340736f

// ---------------- K1: pack weights into 16x16x32 B-frag order ---------------
__global__ __launch_bounds__(256) void pack_weights(
    const float* __restrict__ Wq, const float* __restrict__ Wk,
    const float* __restrict__ Wv, const float* __restrict__ bq,
    const float* __restrict__ bk, const float* __restrict__ bv,
    short* __restrict__ wallF, float* __restrict__ ball)
{
    int n = blockIdx.x;        // 0..319
    int k = threadIdx.x;       // 0..255
    float w;
    if (n < 32)       w = Wq[k * 32 + n];
    else if (n < 64)  w = Wk[k * 32 + (n - 32)] * LOG2E;   // fold log2e into K
    else              w = Wv[k * 256 + (n - 64)];
    int nf = n >> 4, lcol = n & 15;
    int ks = k >> 5, lg = (k >> 3) & 3, e = k & 7;
    wallF[((size_t)(nf * 8 + ks) * 64 + lg * 16 + lcol) * 8 + e] = f2bf(w);
    if (k == 0) {
        float bias = (n < 32) ? bq[n] : (n < 64) ? bk[n - 32] * LOG2E : bv[n - 64];
        ball[n] = bias;
    }
}

// ---------------- K2: QKV projection -> fragment-ordered qF/kF/vF -----------
// Grid 1024 (m16 per block), 4 waves split nf 20 -> 5 each. x rows L1-shared.
__global__ __launch_bounds__(256) void qkv_gemm(
    const float* __restrict__ x, const short* __restrict__ wallF,
    const float* __restrict__ ball,
    short* __restrict__ qf, short* __restrict__ kf, short* __restrict__ vf)
{
    const int w  = threadIdx.x >> 6;
    const int l  = threadIdx.x & 63;
    const int lr = l & 15;             // A row / B col within fragment
    const int lg = l >> 4;             // k-group
    const int m0 = blockIdx.x * 16;

    f32x4 acc[5];
#pragma unroll
    for (int i = 0; i < 5; ++i) acc[i] = (f32x4){0.f, 0.f, 0.f, 0.f};

    const float* xrow = x + (size_t)(m0 + lr) * 256 + lg * 8;
    const short* wwb  = wallF + (size_t)w * 5 * 4096 + l * 8;

#pragma unroll
    for (int ks = 0; ks < 8; ++ks) {
        f32x4 a0 = *(const f32x4*)(xrow + ks * 32);
        f32x4 a1 = *(const f32x4*)(xrow + ks * 32 + 4);
        bf8 af;
#pragma unroll
        for (int t = 0; t < 4; ++t) { af[t] = f2bf(a0[t]); af[t + 4] = f2bf(a1[t]); }
        const short* wb = wwb + (size_t)ks * 512;
#pragma unroll
        for (int nf2 = 0; nf2 < 5; ++nf2) {
            bf8 bfr = *(const bf8*)(wb + (size_t)nf2 * 4096);
            acc[nf2] = __builtin_amdgcn_mfma_f32_16x16x32_bf16(af, bfr, acc[nf2], 0, 0, 0);
        }
    }

    const int b      = m0 >> 12;
    const int i_base = m0 + lg * 4;          // rows i_base..i_base+3
#pragma unroll
    for (int nf2 = 0; nf2 < 5; ++nf2) {
        int nf = w * 5 + nf2;
        int n = nf * 16 + lr;
        float bias = ball[n];
        if (nf < 4) {          // q (nf<2) / k: d = n & 31
            int d = n & 31;
            int f = (d >> 4) & 1, sub = (d >> 3) & 1, e = d & 7;
            short* dst = (nf < 2) ? qf : kf;
            size_t base = ((size_t)(b * 128 + (i_base >> 5)) * 2 + f) * 512 + 256 * sub + e;
#pragma unroll
            for (int r = 0; r < 4; ++r) {
                int i31 = (i_base + r) & 31;
                dst[base + (size_t)i31 * 8] = f2bf(acc[nf2][r] + bias);
            }
        } else {               // v: c = n - 64
            int c = n - 64;
            bf4 pv;
#pragma unroll
            for (int r = 0; r < 4; ++r) pv[r] = f2bf(acc[nf2][r] + bias);
            size_t addr = (size_t)(b * 256 + (i_base >> 4)) * 4096
                        + (size_t)(c >> 5) * 512
                        + (size_t)((c & 31) + 32 * ((i_base >> 3) & 1)) * 8
                        + (i_base & 7);
            *(bf4*)(vf + addr) = pv;
        }
    }
}

// ---------------- K3: Z_i = sum_j 2^(q_i . k_j), swapped operands ------------
// 8 waves split j into 512-chunks; i on lanes, j on regs -> j-reduce in-lane.
__global__ __launch_bounds__(512) void zsum_kernel(
    const short* __restrict__ qF, const short* __restrict__ kF,
    float* __restrict__ zpart)
{
    const int l = threadIdx.x & 63, w = threadIdx.x >> 6;
    const int b = blockIdx.y;
    const int itile = blockIdx.x;            // 0..127

    const short* qp = qF + (size_t)(b * 128 + itile) * 1024 + l * 8;
    bf8 qb0 = *(const bf8*)(qp);
    bf8 qb1 = *(const bf8*)(qp + 512);

    float zacc = 0.f;
    const short* kbase = kF + (size_t)b * 131072 + (size_t)w * 16384 + l * 8;
    for (int jt = 0; jt < 16; ++jt) {
        const short* kp = kbase + jt * 1024;
        bf8 kA0 = *(const bf8*)(kp);
        bf8 kA1 = *(const bf8*)(kp + 512);
        f32x16 S = z16();
        S = __builtin_amdgcn_mfma_f32_32x32x16_bf16(kA0, qb0, S, 0, 0, 0);
        S = __builtin_amdgcn_mfma_f32_32x32x16_bf16(kA1, qb1, S, 0, 0, 0);
#pragma unroll
        for (int r = 0; r < 16; ++r) zacc += exp2_fast(fminf(S[r], 86.f));
    }
    zacc += __shfl_xor(zacc, 32);
    if (l < 32)
        zpart[(size_t)w * 16384 + b * 4096 + itile * 32 + l] = zacc;
}

// ---------------- K3b: rz = 1 / sum(partials) --------------------------------
__global__ __launch_bounds__(256) void zfinish(
    const float* __restrict__ zpart, float* __restrict__ rz)
{
    int i = blockIdx.x * 256 + threadIdx.x;   // 0..16383
    float z = 0.f;
#pragma unroll
    for (int p = 0; p < 8; ++p) z += zpart[p * 16384 + i];
    rz[i] = 1.0f / z;
}

// ---------------- K4: vs = v / Z  (in place on vF) ---------------------------
__global__ __launch_bounds__(256) void vscale(
    short* __restrict__ vF, const float* __restrict__ rz)
{
    int t = blockIdx.x * 256 + threadIdx.x;      // 0..524287
    size_t base = (size_t)t * 8;
    int b   = (int)(base >> 20);
    int rem = (int)(base & 1048575);
    int it  = rem >> 12;
    int sub = (rem >> 8) & 1;                    // lane>>5
    int i0  = it * 16 + sub * 8;
    bf8 v = *(bf8*)(vF + base);
    const float* rzp = rz + b * 4096 + i0;
    f32x4 r0 = *(const f32x4*)(rzp);
    f32x4 r1 = *(const f32x4*)(rzp + 4);
#pragma unroll
    for (int e = 0; e < 4; ++e) {
        v[e]     = f2bf(bf2f(v[e])     * r0[e]);
        v[e + 4] = f2bf(bf2f(v[e + 4]) * r1[e]);
    }
    *(bf8*)(vF + base) = v;
}

// ---------------- K5: out = gamma * (P^T @ vs) + x ---------------------------
// REGISTER MATH (R6/R8/R9 lesson): inner-loop live set ~152 regs (acc 64 AGPR
// + kf 8 + q 8 + v 32 + prefetch 40). 1024-thr block -> cap 512/4 = 128 -> MUST
// spill (was 516 us). 512-thr block -> only 1 block/CU resident (2 waves/SIMD,
// occupancy 17%). Sweet spot: 768-thr block = 12 waves forced co-resident =
// 3 waves/SIMD, cap 512/3 = 170 >= 152 -> fits, no spill.
// Grid 256 = 8 XCD x 32 (1 block/CU): (b = xcd>>1, ch = xcd&1), 32 j-tiles.
// Block 768 = 12 waves = (4 wj) x (3 i-thirds, stride-3 interleave).
// Wave: j32 x c128, ~43 i-steps; softmax in-register; 1/Z folded into vs.
// Epilogue: 2-round LDS reduce across the 3 i-third waves.
__global__ __launch_bounds__(768, 3) void attn_out(
    const short* __restrict__ qF, const short* __restrict__ kF,
    const short* __restrict__ vF,
    const float* __restrict__ x, const float* __restrict__ gammaPtr,
    float* __restrict__ out)
{
    __shared__ float red[4][32][128];            // 64 KB, epilogue only
    const int l = threadIdx.x & 63, w = threadIdx.x >> 6;
    const int lr = l & 31, hi = l >> 5;
    const int wj = w & 3, isub = w >> 2;         // wj 0..3, isub 0..2

    const int xcd = blockIdx.x & 7, jt = blockIdx.x >> 3;   // jt 0..31
    const int b = xcd >> 1, ch = xcd & 1;
    const int j0 = jt * 128;
    const int c0 = ch * 128;

    const short* kfp = kF + (size_t)(b * 128 + jt * 4 + wj) * 1024 + l * 8;
    bf8 kf0 = *(const bf8*)(kfp);
    bf8 kf1 = *(const bf8*)(kfp + 512);

    f32x16 acc[4];
#pragma unroll
    for (int cf = 0; cf < 4; ++cf) acc[cf] = z16();

    const short* qbase = qF + (size_t)b * 131072 + l * 8;
    const short* vbase = vF + (size_t)b * 1048576 + (size_t)(c0 >> 5) * 512 + l * 8;

    // preload first tile (m = isub)
    bf8 q0 = *(const bf8*)(qbase + (size_t)isub * 1024);
    bf8 q1 = *(const bf8*)(qbase + (size_t)isub * 1024 + 512);
    bf8 v0[4], v1[4];
#pragma unroll
    for (int cf = 0; cf < 4; ++cf) {
        v0[cf] = *(const bf8*)(vbase + (size_t)isub * 8192 + cf * 512);
        v1[cf] = *(const bf8*)(vbase + (size_t)isub * 8192 + 4096 + cf * 512);
    }

    for (int m = isub; m < 128; m += 3) {
        bf8 nq0, nq1, nv0[4], nv1[4];
        const int mn = m + 3;
        if (mn < 128) {
            const short* qn = qbase + (size_t)mn * 1024;
            nq0 = *(const bf8*)(qn);
            nq1 = *(const bf8*)(qn + 512);
            const short* vn = vbase + (size_t)mn * 8192;
#pragma unroll
            for (int cf = 0; cf < 4; ++cf) {
                nv0[cf] = *(const bf8*)(vn + cf * 512);
                nv1[cf] = *(const bf8*)(vn + 4096 + cf * 512);
            }
        }

        f32x16 S = z16();
        S = __builtin_amdgcn_mfma_f32_32x32x16_bf16(q0, kf0, S, 0, 0, 0);
        S = __builtin_amdgcn_mfma_f32_32x32x16_bf16(q1, kf1, S, 0, 0, 0);

        float p[16];
#pragma unroll
        for (int r = 0; r < 16; ++r) p[r] = exp2_fast(fminf(S[r], 86.f));

        unsigned X0 = cvtpk(p[0],  p[1]),  Y0 = cvtpk(p[4],  p[5]);
        unsigned X1 = cvtpk(p[2],  p[3]),  Y1 = cvtpk(p[6],  p[7]);
        unsigned X2 = cvtpk(p[8],  p[9]),  Y2 = cvtpk(p[12], p[13]);
        unsigned X3 = cvtpk(p[10], p[11]), Y3 = cvtpk(p[14], p[15]);
        asm("v_permlane32_swap_b32 %0, %1" : "+v"(X0), "+v"(Y0));
        asm("v_permlane32_swap_b32 %0, %1" : "+v"(X1), "+v"(Y1));
        asm("v_permlane32_swap_b32 %0, %1" : "+v"(X2), "+v"(Y2));
        asm("v_permlane32_swap_b32 %0, %1" : "+v"(X3), "+v"(Y3));
        u32x4 a0w = {X0, X1, Y0, Y1};
        u32x4 a1w = {X2, X3, Y2, Y3};
        bf8 A0 = __builtin_bit_cast(bf8, a0w);
        bf8 A1 = __builtin_bit_cast(bf8, a1w);

        __builtin_amdgcn_s_setprio(1);
#pragma unroll
        for (int cf = 0; cf < 4; ++cf) {
            acc[cf] = __builtin_amdgcn_mfma_f32_32x32x16_bf16(A0, v0[cf], acc[cf], 0, 0, 0);
            acc[cf] = __builtin_amdgcn_mfma_f32_32x32x16_bf16(A1, v1[cf], acc[cf], 0, 0, 0);
        }
        __builtin_amdgcn_s_setprio(0);

        q0 = nq0; q1 = nq1;
#pragma unroll
        for (int cf = 0; cf < 4; ++cf) { v0[cf] = nv0[cf]; v1[cf] = nv1[cf]; }
    }

    // epilogue: 2-round reduce of the 3 i-third partials into isub 0
#pragma unroll
    for (int src = 1; src < 3; ++src) {
        if (isub == src) {
#pragma unroll
            for (int cf = 0; cf < 4; ++cf)
#pragma unroll
                for (int r = 0; r < 16; ++r) {
                    int jrow = (r & 3) + 8 * (r >> 2) + 4 * hi;
                    red[wj][jrow][cf * 32 + lr] = acc[cf][r];
                }
        }
        __syncthreads();
        if (isub == 0) {
#pragma unroll
            for (int cf = 0; cf < 4; ++cf)
#pragma unroll
                for (int r = 0; r < 16; ++r) {
                    int jrow = (r & 3) + 8 * (r >> 2) + 4 * hi;
                    acc[cf][r] += red[wj][jrow][cf * 32 + lr];
                }
        }
        __syncthreads();
    }
    if (isub == 0) {
        const float gamma = *gammaPtr;
#pragma unroll
        for (int cf = 0; cf < 4; ++cf)
#pragma unroll
            for (int r = 0; r < 16; ++r) {
                int jrow = (r & 3) + 8 * (r >> 2) + 4 * hi;
                int j = j0 + wj * 32 + jrow;
                size_t idx = (size_t)(b * 4096 + j) * 256 + c0 + cf * 32 + lr;
                out[idx] = gamma * acc[cf][r] + x[idx];
            }
    }
}

extern "C" void kernel_launch(void* const* d_in, const int* in_sizes, int n_in,
                              void* d_out, int out_size, void* d_ws, size_t ws_size,
                              hipStream_t stream)
{
    const float* x  = (const float*)d_in[0];
    const float* Wq = (const float*)d_in[1];
    const float* bq = (const float*)d_in[2];
    const float* Wk = (const float*)d_in[3];
    const float* bk = (const float*)d_in[4];
    const float* Wv = (const float*)d_in[5];
    const float* bv = (const float*)d_in[6];
    const float* gm = (const float*)d_in[7];
    float* out = (float*)d_out;

    char* wsb = (char*)d_ws;
    short* qf    = (short*)(wsb);
    short* kf    = (short*)(wsb + (1u << 20));
    short* vf    = (short*)(wsb + (2u << 20));
    short* wallF = (short*)(wsb + (10u << 20));
    float* ball  = (float*)(wsb + (10u << 20) + 163840);
    float* zpart = (float*)(wsb + (10u << 20) + 163840 + 1280);
    float* rz    = (float*)(wsb + (10u << 20) + 163840 + 1280 + 524288);

    pack_weights<<<320, 256, 0, stream>>>(Wq, Wk, Wv, bq, bk, bv, wallF, ball);
    qkv_gemm<<<1024, 256, 0, stream>>>(x, wallF, ball, qf, kf, vf);
    zsum_kernel<<<dim3(128, 4), 512, 0, stream>>>(qf, kf, zpart);
    zfinish<<<64, 256, 0, stream>>>(zpart, rz);
    vscale<<<2048, 256, 0, stream>>>(vf, rz);
    attn_out<<<256, 768, 0, stream>>>(qf, kf, vf, x, gm, out);
}

// Round 12
// 110.348 us; speedup vs baseline: 5.0146x; 1.0310x over previous
//
#include <hip/hip_runtime.h>
#include <hip/hip_bf16.h>

// B=4, H=W=64 -> N=4096, C=256, d=32
// All MFMA operands stored FRAGMENT-ORDERED so every load is a coalesced
// 1KB wave-load (lane-contiguous base + l*8 shorts).
//
// qF/kF [b][i>>5][f][lane][8] : lane = (i&31)+32*((d>>3)&1), f = d>>4, e = d&7
// vF    [b][i>>4][c>>5][lane][8] : lane = (c&31)+32*((i>>3)&1), e = i&7
// wallF [nf][ks][lane][8] : 16x16x32 B-frags of packed W^T (q|k|v)
// K (and bk) are pre-scaled by log2(e) so softmax uses v_exp_f32 (2^x) directly.
//
// NUMERICS GUARANTEE (R11 lesson): every exp2 input is clamped to <= 86.
// fminf also launders any non-finite S to 86. This bounds p <= 2^86,
// Z <= 2^98, and every P*vs term <= |v| -> acc provably finite. Removing
// the clamp produced NaN (0*inf) in R11. DO NOT REMOVE.
//
// ws layout (bytes):
//   qF    @ 0          1 MB
//   kF    @ 1 MB       1 MB
//   vF    @ 2 MB       8 MB
//   wallF @ 10 MB      160 KB
//   ball  @ +163840    1.25 KB
//   zpart @ +1280      512 KB   [8][16384] f32
//   rz    @ +524288    64 KB

typedef __attribute__((ext_vector_type(4)))  float    f32x4;
typedef __attribute__((ext_vector_type(16))) float    f32x16;
typedef __attribute__((ext_vector_type(8)))  short    bf8;
typedef __attribute__((ext_vector_type(4)))  short    bf4;
typedef __attribute__((ext_vector_type(4)))  unsigned u32x4;

__device__ __forceinline__ short f2bf(float f) {
    unsigned u = __builtin_bit_cast(unsigned, f);
    u += 0x7FFF + ((u >> 16) & 1);           // RNE
    return (short)(u >> 16);
}
__device__ __forceinline__ float bf2f(short h) {
    unsigned u = ((unsigned)(unsigned short)h) << 16;
    return __builtin_bit_cast(float, u);
}
__device__ __forceinline__ unsigned cvtpk(float lo, float hi) {
    unsigned r;
    asm("v_cvt_pk_bf16_f32 %0, %1, %2" : "=v"(r) : "v"(lo), "v"(hi));
    return r;
}
__device__ __forceinline__ float exp2_fast(float x) {   // 2^x, one v_exp_f32
    float r;
    asm("v_exp_f32 %0, %1" : "=v"(r) : "v"(x));
    return r;
}
__device__ __forceinline__ f32x16 z16() {
    f32x16 v;
#pragma unroll
    for (int i = 0; i < 16; ++i) v[i] = 0.f;
    return v;
}

#define LOG2E 1.44269504088896340736f

// ---------------- K1: pack weights into 16x16x32 B-frag order ---------------
__global__ __launch_bounds__(256) void pack_weights(
    const float* __restrict__ Wq, const float* __restrict__ Wk,
    const float* __restrict__ Wv, const float* __restrict__ bq,
    const float* __restrict__ bk, const float* __restrict__ bv,
    short* __restrict__ wallF, float* __restrict__ ball)
{
    int n = blockIdx.x;        // 0..319
    int k = threadIdx.x;       // 0..255
    float w;
    if (n < 32)       w = Wq[k * 32 + n];
    else if (n < 64)  w = Wk[k * 32 + (n - 32)] * LOG2E;   // fold log2e into K
    else              w = Wv[k * 256 + (n - 64)];
    int nf = n >> 4, lcol = n & 15;
    int ks = k >> 5, lg = (k >> 3) & 3, e = k & 7;
    wallF[((size_t)(nf * 8 + ks) * 64 + lg * 16 + lcol) * 8 + e] = f2bf(w);
    if (k == 0) {
        float bias = (n < 32) ? bq[n] : (n < 64) ? bk[n - 32] * LOG2E : bv[n - 64];
        ball[n] = bias;
    }
}

// ---------------- K2: QKV projection -> fragment-ordered qF/kF/vF -----------
// Grid 1024 (m16 per block), 4 waves split nf 20 -> 5 each. x rows L1-shared.
__global__ __launch_bounds__(256) void qkv_gemm(
    const float* __restrict__ x, const short* __restrict__ wallF,
    const float* __restrict__ ball,
    short* __restrict__ qf, short* __restrict__ kf, short* __restrict__ vf)
{
    const int w  = threadIdx.x >> 6;
    const int l  = threadIdx.x & 63;
    const int lr = l & 15;             // A row / B col within fragment
    const int lg = l >> 4;             // k-group
    const int m0 = blockIdx.x * 16;

    f32x4 acc[5];
#pragma unroll
    for (int i = 0; i < 5; ++i) acc[i] = (f32x4){0.f, 0.f, 0.f, 0.f};

    const float* xrow = x + (size_t)(m0 + lr) * 256 + lg * 8;
    const short* wwb  = wallF + (size_t)w * 5 * 4096 + l * 8;

#pragma unroll
    for (int ks = 0; ks < 8; ++ks) {
        f32x4 a0 = *(const f32x4*)(xrow + ks * 32);
        f32x4 a1 = *(const f32x4*)(xrow + ks * 32 + 4);
        bf8 af;
#pragma unroll
        for (int t = 0; t < 4; ++t) { af[t] = f2bf(a0[t]); af[t + 4] = f2bf(a1[t]); }
        const short* wb = wwb + (size_t)ks * 512;
#pragma unroll
        for (int nf2 = 0; nf2 < 5; ++nf2) {
            bf8 bfr = *(const bf8*)(wb + (size_t)nf2 * 4096);
            acc[nf2] = __builtin_amdgcn_mfma_f32_16x16x32_bf16(af, bfr, acc[nf2], 0, 0, 0);
        }
    }

    const int b      = m0 >> 12;
    const int i_base = m0 + lg * 4;          // rows i_base..i_base+3
#pragma unroll
    for (int nf2 = 0; nf2 < 5; ++nf2) {
        int nf = w * 5 + nf2;
        int n = nf * 16 + lr;
        float bias = ball[n];
        if (nf < 4) {          // q (nf<2) / k: d = n & 31
            int d = n & 31;
            int f = (d >> 4) & 1, sub = (d >> 3) & 1, e = d & 7;
            short* dst = (nf < 2) ? qf : kf;
            size_t base = ((size_t)(b * 128 + (i_base >> 5)) * 2 + f) * 512 + 256 * sub + e;
#pragma unroll
            for (int r = 0; r < 4; ++r) {
                int i31 = (i_base + r) & 31;
                dst[base + (size_t)i31 * 8] = f2bf(acc[nf2][r] + bias);
            }
        } else {               // v: c = n - 64
            int c = n - 64;
            bf4 pv;
#pragma unroll
            for (int r = 0; r < 4; ++r) pv[r] = f2bf(acc[nf2][r] + bias);
            size_t addr = (size_t)(b * 256 + (i_base >> 4)) * 4096
                        + (size_t)(c >> 5) * 512
                        + (size_t)((c & 31) + 32 * ((i_base >> 3) & 1)) * 8
                        + (i_base & 7);
            *(bf4*)(vf + addr) = pv;
        }
    }
}

// ---------------- K3: Z_i = sum_j 2^(q_i . k_j), swapped operands ------------
// Grid (64,4): 2 q-tiles per block share each streamed K tile (halves K loads).
// 8 waves split j into 2048-chunks of 512; i on lanes, j on regs.
__global__ __launch_bounds__(512) void zsum_kernel(
    const short* __restrict__ qF, const short* __restrict__ kF,
    float* __restrict__ zpart)
{
    const int l = threadIdx.x & 63, w = threadIdx.x >> 6;
    const int b = blockIdx.y;
    const int it0 = blockIdx.x * 2;          // 0,2,..,126

    const short* qpa = qF + (size_t)(b * 128 + it0) * 1024 + l * 8;
    bf8 qa0 = *(const bf8*)(qpa);
    bf8 qa1 = *(const bf8*)(qpa + 512);
    bf8 qb0 = *(const bf8*)(qpa + 1024);
    bf8 qb1 = *(const bf8*)(qpa + 1536);

    float zA = 0.f, zB = 0.f;
    const short* kbase = kF + (size_t)b * 131072 + (size_t)w * 16384 + l * 8;
    for (int jt = 0; jt < 16; ++jt) {
        const short* kp = kbase + jt * 1024;
        bf8 kA0 = *(const bf8*)(kp);
        bf8 kA1 = *(const bf8*)(kp + 512);
        f32x16 SA = z16(), SB = z16();
        SA = __builtin_amdgcn_mfma_f32_32x32x16_bf16(kA0, qa0, SA, 0, 0, 0);
        SA = __builtin_amdgcn_mfma_f32_32x32x16_bf16(kA1, qa1, SA, 0, 0, 0);
        SB = __builtin_amdgcn_mfma_f32_32x32x16_bf16(kA0, qb0, SB, 0, 0, 0);
        SB = __builtin_amdgcn_mfma_f32_32x32x16_bf16(kA1, qb1, SB, 0, 0, 0);
#pragma unroll
        for (int r = 0; r < 16; ++r) {
            zA += exp2_fast(fminf(SA[r], 86.f));   // clamp: finiteness guarantee
            zB += exp2_fast(fminf(SB[r], 86.f));
        }
    }
    zA += __shfl_xor(zA, 32);
    zB += __shfl_xor(zB, 32);
    if (l < 32) {
        zpart[(size_t)w * 16384 + b * 4096 + it0 * 32 + l]      = zA;
        zpart[(size_t)w * 16384 + b * 4096 + it0 * 32 + 32 + l] = zB;
    }
}

// ---------------- K3b: rz = 1 / sum(partials) --------------------------------
__global__ __launch_bounds__(256) void zfinish(
    const float* __restrict__ zpart, float* __restrict__ rz)
{
    int i = blockIdx.x * 256 + threadIdx.x;   // 0..16383
    float z = 0.f;
#pragma unroll
    for (int p = 0; p < 8; ++p) z += zpart[p * 16384 + i];
    rz[i] = 1.0f / z;
}

// ---------------- K4: vs = v / Z  (in place on vF) ---------------------------
__global__ __launch_bounds__(256) void vscale(
    short* __restrict__ vF, const float* __restrict__ rz)
{
    int t = blockIdx.x * 256 + threadIdx.x;      // 0..524287
    size_t base = (size_t)t * 8;
    int b   = (int)(base >> 20);
    int rem = (int)(base & 1048575);
    int it  = rem >> 12;
    int sub = (rem >> 8) & 1;                    // lane>>5
    int i0  = it * 16 + sub * 8;
    bf8 v = *(bf8*)(vF + base);
    const float* rzp = rz + b * 4096 + i0;
    f32x4 r0 = *(const f32x4*)(rzp);
    f32x4 r1 = *(const f32x4*)(rzp + 4);
#pragma unroll
    for (int e = 0; e < 4; ++e) {
        v[e]     = f2bf(bf2f(v[e])     * r0[e]);
        v[e + 4] = f2bf(bf2f(v[e + 4]) * r1[e]);
    }
    *(bf8*)(vF + base) = v;
}

// ---------------- K5: out = gamma * (P^T @ vs) + x ---------------------------
// LOAD-REUSE (R10 lesson: TA/load-bound, V fetched once per PV MFMA).
// Wave holds j=128 (4 K-subtiles in regs): each V fragment feeds 4 PV MFMAs
// -> 256 B/MFMA; chip loads 1.35 GB -> ~400 MB. acc = 4jf x 2cf x f32x16 =
// 128 AGPR -> 2 waves/SIMD (512-thr block).
// Grid 256 = 8 XCD x 32 (1 block/CU): b = xcd>>1, ch = xcd&1, 32 j-tiles of 128.
// Block 512 = 8 waves = (2 wc: c64 each) x (4 isub: i-quarters, stride-4).
// Epilogue: 3-round LDS reduce over isub.
__global__ __launch_bounds__(512) void attn_out(
    const short* __restrict__ qF, const short* __restrict__ kF,
    const short* __restrict__ vF,
    const float* __restrict__ x, const float* __restrict__ gammaPtr,
    float* __restrict__ out)
{
    __shared__ float red[2][128][64];            // 64 KB, epilogue only
    const int l = threadIdx.x & 63, w = threadIdx.x >> 6;
    const int lr = l & 31, hi = l >> 5;
    const int wc = w & 1, isub = w >> 1;         // wc 0..1, isub 0..3

    const int xcd = blockIdx.x & 7, jt = blockIdx.x >> 3;   // jt 0..31
    const int b = xcd >> 1, ch = xcd & 1;
    const int j0 = jt * 128;
    const int c0 = ch * 128 + wc * 64;

    // persistent K frags for 4 j-subtiles (32 VGPR)
    bf8 kf0[4], kf1[4];
#pragma unroll
    for (int jf = 0; jf < 4; ++jf) {
        const short* kfp = kF + (size_t)(b * 128 + jt * 4 + jf) * 1024 + l * 8;
        kf0[jf] = *(const bf8*)(kfp);
        kf1[jf] = *(const bf8*)(kfp + 512);
    }

    f32x16 acc[4][2];
#pragma unroll
    for (int jf = 0; jf < 4; ++jf)
#pragma unroll
        for (int cf = 0; cf < 2; ++cf) acc[jf][cf] = z16();

    const short* qbase = qF + (size_t)b * 131072 + l * 8;
    const short* vbase = vF + (size_t)b * 1048576 + (size_t)(c0 >> 5) * 512 + l * 8;

    // preload first tile's q and v0-pair (m = isub)
    bf8 q0 = *(const bf8*)(qbase + (size_t)isub * 1024);
    bf8 q1 = *(const bf8*)(qbase + (size_t)isub * 1024 + 512);
    bf8 v00 = *(const bf8*)(vbase + (size_t)isub * 8192);
    bf8 v01 = *(const bf8*)(vbase + (size_t)isub * 8192 + 512);

    for (int t = 0; t < 32; ++t) {
        const int m = isub + t * 4;
        const short* vp = vbase + (size_t)m * 8192;
        // v1-pair for CURRENT step: consumed after QK+exp (~300cy) -> covered
        bf8 cv10 = *(const bf8*)(vp + 4096);
        bf8 cv11 = *(const bf8*)(vp + 4096 + 512);
        bf8 nq0 = q0, nq1 = q1, nv00 = v00, nv01 = v01;   // UB-safe tail
        if (t < 31) {
            const short* qn = qbase + (size_t)(m + 4) * 1024;
            nq0 = *(const bf8*)(qn);
            nq1 = *(const bf8*)(qn + 512);
            const short* vn = vbase + (size_t)(m + 4) * 8192;
            nv00 = *(const bf8*)(vn);
            nv01 = *(const bf8*)(vn + 512);
        }

#pragma unroll
        for (int jf = 0; jf < 4; ++jf) {
            f32x16 S = z16();
            S = __builtin_amdgcn_mfma_f32_32x32x16_bf16(q0, kf0[jf], S, 0, 0, 0);
            S = __builtin_amdgcn_mfma_f32_32x32x16_bf16(q1, kf1[jf], S, 0, 0, 0);

            float p[16];
#pragma unroll
            for (int r = 0; r < 16; ++r) p[r] = exp2_fast(fminf(S[r], 86.f));

            unsigned X0 = cvtpk(p[0],  p[1]),  Y0 = cvtpk(p[4],  p[5]);
            unsigned X1 = cvtpk(p[2],  p[3]),  Y1 = cvtpk(p[6],  p[7]);
            unsigned X2 = cvtpk(p[8],  p[9]),  Y2 = cvtpk(p[12], p[13]);
            unsigned X3 = cvtpk(p[10], p[11]), Y3 = cvtpk(p[14], p[15]);
            asm("v_permlane32_swap_b32 %0, %1" : "+v"(X0), "+v"(Y0));
            asm("v_permlane32_swap_b32 %0, %1" : "+v"(X1), "+v"(Y1));
            asm("v_permlane32_swap_b32 %0, %1" : "+v"(X2), "+v"(Y2));
            asm("v_permlane32_swap_b32 %0, %1" : "+v"(X3), "+v"(Y3));
            u32x4 a0w = {X0, X1, Y0, Y1};
            u32x4 a1w = {X2, X3, Y2, Y3};
            bf8 A0 = __builtin_bit_cast(bf8, a0w);
            bf8 A1 = __builtin_bit_cast(bf8, a1w);

            __builtin_amdgcn_s_setprio(1);
            acc[jf][0] = __builtin_amdgcn_mfma_f32_32x32x16_bf16(A0, v00,  acc[jf][0], 0, 0, 0);
            acc[jf][0] = __builtin_amdgcn_mfma_f32_32x32x16_bf16(A1, cv10, acc[jf][0], 0, 0, 0);
            acc[jf][1] = __builtin_amdgcn_mfma_f32_32x32x16_bf16(A0, v01,  acc[jf][1], 0, 0, 0);
            acc[jf][1] = __builtin_amdgcn_mfma_f32_32x32x16_bf16(A1, cv11, acc[jf][1], 0, 0, 0);
            __builtin_amdgcn_s_setprio(0);
        }

        q0 = nq0; q1 = nq1; v00 = nv00; v01 = nv01;
    }

    // epilogue: 3-round reduce of the 4 i-quarter partials into isub 0
#pragma unroll
    for (int src = 1; src < 4; ++src) {
        if (isub == src) {
#pragma unroll
            for (int jf = 0; jf < 4; ++jf)
#pragma unroll
                for (int cf = 0; cf < 2; ++cf)
#pragma unroll
                    for (int r = 0; r < 16; ++r) {
                        int jrow = (r & 3) + 8 * (r >> 2) + 4 * hi;
                        red[wc][jf * 32 + jrow][cf * 32 + lr] = acc[jf][cf][r];
                    }
        }
        __syncthreads();
        if (isub == 0) {
#pragma unroll
            for (int jf = 0; jf < 4; ++jf)
#pragma unroll
                for (int cf = 0; cf < 2; ++cf)
#pragma unroll
                    for (int r = 0; r < 16; ++r) {
                        int jrow = (r & 3) + 8 * (r >> 2) + 4 * hi;
                        acc[jf][cf][r] += red[wc][jf * 32 + jrow][cf * 32 + lr];
                    }
        }
        __syncthreads();
    }
    if (isub == 0) {
        const float gamma = *gammaPtr;
#pragma unroll
        for (int jf = 0; jf < 4; ++jf)
#pragma unroll
            for (int cf = 0; cf < 2; ++cf)
#pragma unroll
                for (int r = 0; r < 16; ++r) {
                    int jrow = (r & 3) + 8 * (r >> 2) + 4 * hi;
                    int j = j0 + jf * 32 + jrow;
                    size_t idx = (size_t)(b * 4096 + j) * 256 + c0 + cf * 32 + lr;
                    out[idx] = gamma * acc[jf][cf][r] + x[idx];
                }
    }
}

extern "C" void kernel_launch(void* const* d_in, const int* in_sizes, int n_in,
                              void* d_out, int out_size, void* d_ws, size_t ws_size,
                              hipStream_t stream)
{
    const float* x  = (const float*)d_in[0];
    const float* Wq = (const float*)d_in[1];
    const float* bq = (const float*)d_in[2];
    const float* Wk = (const float*)d_in[3];
    const float* bk = (const float*)d_in[4];
    const float* Wv = (const float*)d_in[5];
    const float* bv = (const float*)d_in[6];
    const float* gm = (const float*)d_in[7];
    float* out = (float*)d_out;

    char* wsb = (char*)d_ws;
    short* qf    = (short*)(wsb);
    short* kf    = (short*)(wsb + (1u << 20));
    short* vf    = (short*)(wsb + (2u << 20));
    short* wallF = (short*)(wsb + (10u << 20));
    float* ball  = (float*)(wsb + (10u << 20) + 163840);
    float* zpart = (float*)(wsb + (10u << 20) + 163840 + 1280);
    float* rz    = (float*)(wsb + (10u << 20) + 163840 + 1280 + 524288);

    pack_weights<<<320, 256, 0, stream>>>(Wq, Wk, Wv, bq, bk, bv, wallF, ball);
    qkv_gemm<<<1024, 256, 0, stream>>>(x, wallF, ball, qf, kf, vf);
    zsum_kernel<<<dim3(64, 4), 512, 0, stream>>>(qf, kf, zpart);
    zfinish<<<64, 256, 0, stream>>>(zpart, rz);
    vscale<<<2048, 256, 0, stream>>>(vf, rz);
    attn_out<<<256, 512, 0, stream>>>(qf, kf, vf, x, gm, out);
}

// Round 13
// 98.701 us; speedup vs baseline: 5.6063x; 1.1180x over previous
//
#include <hip/hip_runtime.h>
#include <hip/hip_bf16.h>

// B=4, H=W=64 -> N=4096, C=256, d=32
// All MFMA operands stored FRAGMENT-ORDERED so every load is a coalesced
// 1KB wave-load (lane-contiguous base + l*8 shorts).
//
// qF/kF [b][i>>5][f][lane][8] : lane = (i&31)+32*((d>>3)&1), f = d>>4, e = d&7
// vF    [b][i>>4][c>>5][lane][8] : lane = (c&31)+32*((i>>3)&1), e = i&7
// wallF [nf][ks][lane][8] : 16x16x32 B-frags of packed W^T (q|k|v)
// K (and bk) are pre-scaled by log2(e) so softmax uses v_exp_f32 (2^x) directly.
//
// NUMERICS GUARANTEE (R11 lesson): every exp2 input is clamped to <= 86.
// fminf also launders any non-finite S to 86. This bounds p <= 2^86,
// Z <= 2^98, and every P*vs term <= |v| -> acc provably finite. Removing
// the clamp produced NaN (0*inf) in R11. DO NOT REMOVE.
//
// ws layout (bytes):
//   qF    @ 0          1 MB
//   kF    @ 1 MB       1 MB
//   vF    @ 2 MB       8 MB
//   wallF @ 10 MB      160 KB
//   ball  @ +163840    1.25 KB
//   zpart @ +1280      512 KB   [8][16384] f32
//   rz    @ +524288    64 KB

typedef __attribute__((ext_vector_type(4)))  float    f32x4;
typedef __attribute__((ext_vector_type(16))) float    f32x16;
typedef __attribute__((ext_vector_type(8)))  short    bf8;
typedef __attribute__((ext_vector_type(4)))  short    bf4;
typedef __attribute__((ext_vector_type(4)))  unsigned u32x4;

__device__ __forceinline__ short f2bf(float f) {
    unsigned u = __builtin_bit_cast(unsigned, f);
    u += 0x7FFF + ((u >> 16) & 1);           // RNE
    return (short)(u >> 16);
}
__device__ __forceinline__ float bf2f(short h) {
    unsigned u = ((unsigned)(unsigned short)h) << 16;
    return __builtin_bit_cast(float, u);
}
__device__ __forceinline__ unsigned cvtpk(float lo, float hi) {
    unsigned r;
    asm("v_cvt_pk_bf16_f32 %0, %1, %2" : "=v"(r) : "v"(lo), "v"(hi));
    return r;
}
__device__ __forceinline__ float exp2_fast(float x) {   // 2^x, one v_exp_f32
    float r;
    asm("v_exp_f32 %0, %1" : "=v"(r) : "v"(x));
    return r;
}
__device__ __forceinline__ f32x16 z16() {
    f32x16 v;
#pragma unroll
    for (int i = 0; i < 16; ++i) v[i] = 0.f;
    return v;
}

#define LOG2E 1.44269504088896340736f

// ---------------- K1: pack weights into 16x16x32 B-frag order ---------------
__global__ __launch_bounds__(256) void pack_weights(
    const float* __restrict__ Wq, const float* __restrict__ Wk,
    const float* __restrict__ Wv, const float* __restrict__ bq,
    const float* __restrict__ bk, const float* __restrict__ bv,
    short* __restrict__ wallF, float* __restrict__ ball)
{
    int n = blockIdx.x;        // 0..319
    int k = threadIdx.x;       // 0..255
    float w;
    if (n < 32)       w = Wq[k * 32 + n];
    else if (n < 64)  w = Wk[k * 32 + (n - 32)] * LOG2E;   // fold log2e into K
    else              w = Wv[k * 256 + (n - 64)];
    int nf = n >> 4, lcol = n & 15;
    int ks = k >> 5, lg = (k >> 3) & 3, e = k & 7;
    wallF[((size_t)(nf * 8 + ks) * 64 + lg * 16 + lcol) * 8 + e] = f2bf(w);
    if (k == 0) {
        float bias = (n < 32) ? bq[n] : (n < 64) ? bk[n - 32] * LOG2E : bv[n - 64];
        ball[n] = bias;
    }
}

// ---------------- K2: QKV projection -> fragment-ordered qF/kF/vF -----------
// Grid 1024 (m16 per block), 4 waves split nf 20 -> 5 each. x rows L1-shared.
__global__ __launch_bounds__(256) void qkv_gemm(
    const float* __restrict__ x, const short* __restrict__ wallF,
    const float* __restrict__ ball,
    short* __restrict__ qf, short* __restrict__ kf, short* __restrict__ vf)
{
    const int w  = threadIdx.x >> 6;
    const int l  = threadIdx.x & 63;
    const int lr = l & 15;             // A row / B col within fragment
    const int lg = l >> 4;             // k-group
    const int m0 = blockIdx.x * 16;

    f32x4 acc[5];
#pragma unroll
    for (int i = 0; i < 5; ++i) acc[i] = (f32x4){0.f, 0.f, 0.f, 0.f};

    const float* xrow = x + (size_t)(m0 + lr) * 256 + lg * 8;
    const short* wwb  = wallF + (size_t)w * 5 * 4096 + l * 8;

#pragma unroll
    for (int ks = 0; ks < 8; ++ks) {
        f32x4 a0 = *(const f32x4*)(xrow + ks * 32);
        f32x4 a1 = *(const f32x4*)(xrow + ks * 32 + 4);
        bf8 af;
#pragma unroll
        for (int t = 0; t < 4; ++t) { af[t] = f2bf(a0[t]); af[t + 4] = f2bf(a1[t]); }
        const short* wb = wwb + (size_t)ks * 512;
#pragma unroll
        for (int nf2 = 0; nf2 < 5; ++nf2) {
            bf8 bfr = *(const bf8*)(wb + (size_t)nf2 * 4096);
            acc[nf2] = __builtin_amdgcn_mfma_f32_16x16x32_bf16(af, bfr, acc[nf2], 0, 0, 0);
        }
    }

    const int b      = m0 >> 12;
    const int i_base = m0 + lg * 4;          // rows i_base..i_base+3
#pragma unroll
    for (int nf2 = 0; nf2 < 5; ++nf2) {
        int nf = w * 5 + nf2;
        int n = nf * 16 + lr;
        float bias = ball[n];
        if (nf < 4) {          // q (nf<2) / k: d = n & 31
            int d = n & 31;
            int f = (d >> 4) & 1, sub = (d >> 3) & 1, e = d & 7;
            short* dst = (nf < 2) ? qf : kf;
            size_t base = ((size_t)(b * 128 + (i_base >> 5)) * 2 + f) * 512 + 256 * sub + e;
#pragma unroll
            for (int r = 0; r < 4; ++r) {
                int i31 = (i_base + r) & 31;
                dst[base + (size_t)i31 * 8] = f2bf(acc[nf2][r] + bias);
            }
        } else {               // v: c = n - 64
            int c = n - 64;
            bf4 pv;
#pragma unroll
            for (int r = 0; r < 4; ++r) pv[r] = f2bf(acc[nf2][r] + bias);
            size_t addr = (size_t)(b * 256 + (i_base >> 4)) * 4096
                        + (size_t)(c >> 5) * 512
                        + (size_t)((c & 31) + 32 * ((i_base >> 3) & 1)) * 8
                        + (i_base & 7);
            *(bf4*)(vf + addr) = pv;
        }
    }
}

// ---------------- K3: Z_i = sum_j 2^(q_i . k_j), swapped operands ------------
// Grid (64,4): 2 q-tiles per block share each streamed K tile (halves K loads).
// 8 waves split j into 2048-chunks of 512; i on lanes, j on regs.
__global__ __launch_bounds__(512) void zsum_kernel(
    const short* __restrict__ qF, const short* __restrict__ kF,
    float* __restrict__ zpart)
{
    const int l = threadIdx.x & 63, w = threadIdx.x >> 6;
    const int b = blockIdx.y;
    const int it0 = blockIdx.x * 2;          // 0,2,..,126

    const short* qpa = qF + (size_t)(b * 128 + it0) * 1024 + l * 8;
    bf8 qa0 = *(const bf8*)(qpa);
    bf8 qa1 = *(const bf8*)(qpa + 512);
    bf8 qb0 = *(const bf8*)(qpa + 1024);
    bf8 qb1 = *(const bf8*)(qpa + 1536);

    float zA = 0.f, zB = 0.f;
    const short* kbase = kF + (size_t)b * 131072 + (size_t)w * 16384 + l * 8;
    for (int jt = 0; jt < 16; ++jt) {
        const short* kp = kbase + jt * 1024;
        bf8 kA0 = *(const bf8*)(kp);
        bf8 kA1 = *(const bf8*)(kp + 512);
        f32x16 SA = z16(), SB = z16();
        SA = __builtin_amdgcn_mfma_f32_32x32x16_bf16(kA0, qa0, SA, 0, 0, 0);
        SA = __builtin_amdgcn_mfma_f32_32x32x16_bf16(kA1, qa1, SA, 0, 0, 0);
        SB = __builtin_amdgcn_mfma_f32_32x32x16_bf16(kA0, qb0, SB, 0, 0, 0);
        SB = __builtin_amdgcn_mfma_f32_32x32x16_bf16(kA1, qb1, SB, 0, 0, 0);
#pragma unroll
        for (int r = 0; r < 16; ++r) {
            zA += exp2_fast(fminf(SA[r], 86.f));   // clamp: finiteness guarantee
            zB += exp2_fast(fminf(SB[r], 86.f));
        }
    }
    zA += __shfl_xor(zA, 32);
    zB += __shfl_xor(zB, 32);
    if (l < 32) {
        zpart[(size_t)w * 16384 + b * 4096 + it0 * 32 + l]      = zA;
        zpart[(size_t)w * 16384 + b * 4096 + it0 * 32 + 32 + l] = zB;
    }
}

// ---------------- K3b: rz = 1 / sum(partials) --------------------------------
__global__ __launch_bounds__(256) void zfinish(
    const float* __restrict__ zpart, float* __restrict__ rz)
{
    int i = blockIdx.x * 256 + threadIdx.x;   // 0..16383
    float z = 0.f;
#pragma unroll
    for (int p = 0; p < 8; ++p) z += zpart[p * 16384 + i];
    rz[i] = 1.0f / z;
}

// ---------------- K4: vs = v / Z  (in place on vF) ---------------------------
__global__ __launch_bounds__(256) void vscale(
    short* __restrict__ vF, const float* __restrict__ rz)
{
    int t = blockIdx.x * 256 + threadIdx.x;      // 0..524287
    size_t base = (size_t)t * 8;
    int b   = (int)(base >> 20);
    int rem = (int)(base & 1048575);
    int it  = rem >> 12;
    int sub = (rem >> 8) & 1;                    // lane>>5
    int i0  = it * 16 + sub * 8;
    bf8 v = *(bf8*)(vF + base);
    const float* rzp = rz + b * 4096 + i0;
    f32x4 r0 = *(const f32x4*)(rzp);
    f32x4 r1 = *(const f32x4*)(rzp + 4);
#pragma unroll
    for (int e = 0; e < 4; ++e) {
        v[e]     = f2bf(bf2f(v[e])     * r0[e]);
        v[e + 4] = f2bf(bf2f(v[e + 4]) * r1[e]);
    }
    *(bf8*)(vF + base) = v;
}

// ---------------- K5: out = gamma * (P^T @ vs) + x ---------------------------
// DUP-REDUCTION RESHAPE (R12 lesson: softmax VALU is the top cost; the
// j128 x c64 wave computed each exp(S(i,j)) 4x chip-wide (2 ch x 2 wc)).
// Wave is now j64 x c128: one block owns FULL C=256 for its j-tile of 64,
// so each (i,j) exp is computed only 2x (wc split). Attn exp 268M -> 134M,
// QK MFMA halves. Cost: V traffic 256 -> 512 MB (still L2-resident:
// ~2.5 MB/XCD working set). acc = 2jf x 4cf x f32x16 = 128 AGPR unchanged
// -> 2 waves/SIMD (512-thr block, 256-reg cap, ~120 VGPR, no spill).
// Grid 256 = 8 XCD x 32 (1 block/CU): b = xcd>>1, jt = (xcd&1)*32 + k.
// Block 512 = 8 waves = (2 wc: c128 each) x (4 isub: i-quarters, stride-4).
// Epilogue: 3-round LDS reduce over isub.
__global__ __launch_bounds__(512) void attn_out(
    const short* __restrict__ qF, const short* __restrict__ kF,
    const short* __restrict__ vF,
    const float* __restrict__ x, const float* __restrict__ gammaPtr,
    float* __restrict__ out)
{
    __shared__ float red[2][64][128];            // 64 KB, epilogue only
    const int l = threadIdx.x & 63, w = threadIdx.x >> 6;
    const int lr = l & 31, hi = l >> 5;
    const int wc = w & 1, isub = w >> 1;         // wc 0..1, isub 0..3

    const int xcd = blockIdx.x & 7, k = blockIdx.x >> 3;    // k 0..31
    const int b = xcd >> 1;
    const int jt = (xcd & 1) * 32 + k;           // 0..63, j-tile of 64
    const int j0 = jt * 64;
    const int c0 = wc * 128;

    // persistent K frags for 2 j-subtiles (16 VGPR)
    bf8 kf0[2], kf1[2];
#pragma unroll
    for (int jf = 0; jf < 2; ++jf) {
        const short* kfp = kF + (size_t)(b * 128 + jt * 2 + jf) * 1024 + l * 8;
        kf0[jf] = *(const bf8*)(kfp);
        kf1[jf] = *(const bf8*)(kfp + 512);
    }

    f32x16 acc[2][4];
#pragma unroll
    for (int jf = 0; jf < 2; ++jf)
#pragma unroll
        for (int cf = 0; cf < 4; ++cf) acc[jf][cf] = z16();

    const short* qbase = qF + (size_t)b * 131072 + l * 8;
    const short* vbase = vF + (size_t)b * 1048576 + (size_t)(c0 >> 5) * 512 + l * 8;

    // preload first tile's q and first-itile V quad (m = isub)
    bf8 q0 = *(const bf8*)(qbase + (size_t)isub * 1024);
    bf8 q1 = *(const bf8*)(qbase + (size_t)isub * 1024 + 512);
    bf8 v0[4];
#pragma unroll
    for (int cf = 0; cf < 4; ++cf)
        v0[cf] = *(const bf8*)(vbase + (size_t)isub * 8192 + cf * 512);

    for (int t = 0; t < 32; ++t) {
        const int m = isub + t * 4;
        const short* vp = vbase + (size_t)m * 8192;
        // second-itile V quad for CURRENT step: consumed after QK+exp -> covered
        bf8 cv1[4];
#pragma unroll
        for (int cf = 0; cf < 4; ++cf)
            cv1[cf] = *(const bf8*)(vp + 4096 + cf * 512);
        bf8 nq0 = q0, nq1 = q1, nv0[4];          // UB-safe tail
#pragma unroll
        for (int cf = 0; cf < 4; ++cf) nv0[cf] = v0[cf];
        if (t < 31) {
            const short* qn = qbase + (size_t)(m + 4) * 1024;
            nq0 = *(const bf8*)(qn);
            nq1 = *(const bf8*)(qn + 512);
            const short* vn = vbase + (size_t)(m + 4) * 8192;
#pragma unroll
            for (int cf = 0; cf < 4; ++cf)
                nv0[cf] = *(const bf8*)(vn + cf * 512);
        }

#pragma unroll
        for (int jf = 0; jf < 2; ++jf) {
            f32x16 S = z16();
            S = __builtin_amdgcn_mfma_f32_32x32x16_bf16(q0, kf0[jf], S, 0, 0, 0);
            S = __builtin_amdgcn_mfma_f32_32x32x16_bf16(q1, kf1[jf], S, 0, 0, 0);

            float p[16];
#pragma unroll
            for (int r = 0; r < 16; ++r) p[r] = exp2_fast(fminf(S[r], 86.f));

            unsigned X0 = cvtpk(p[0],  p[1]),  Y0 = cvtpk(p[4],  p[5]);
            unsigned X1 = cvtpk(p[2],  p[3]),  Y1 = cvtpk(p[6],  p[7]);
            unsigned X2 = cvtpk(p[8],  p[9]),  Y2 = cvtpk(p[12], p[13]);
            unsigned X3 = cvtpk(p[10], p[11]), Y3 = cvtpk(p[14], p[15]);
            asm("v_permlane32_swap_b32 %0, %1" : "+v"(X0), "+v"(Y0));
            asm("v_permlane32_swap_b32 %0, %1" : "+v"(X1), "+v"(Y1));
            asm("v_permlane32_swap_b32 %0, %1" : "+v"(X2), "+v"(Y2));
            asm("v_permlane32_swap_b32 %0, %1" : "+v"(X3), "+v"(Y3));
            u32x4 a0w = {X0, X1, Y0, Y1};
            u32x4 a1w = {X2, X3, Y2, Y3};
            bf8 A0 = __builtin_bit_cast(bf8, a0w);
            bf8 A1 = __builtin_bit_cast(bf8, a1w);

            __builtin_amdgcn_s_setprio(1);
#pragma unroll
            for (int cf = 0; cf < 4; ++cf) {
                acc[jf][cf] = __builtin_amdgcn_mfma_f32_32x32x16_bf16(A0, v0[cf],  acc[jf][cf], 0, 0, 0);
                acc[jf][cf] = __builtin_amdgcn_mfma_f32_32x32x16_bf16(A1, cv1[cf], acc[jf][cf], 0, 0, 0);
            }
            __builtin_amdgcn_s_setprio(0);
        }

        q0 = nq0; q1 = nq1;
#pragma unroll
        for (int cf = 0; cf < 4; ++cf) v0[cf] = nv0[cf];
    }

    // epilogue: 3-round reduce of the 4 i-quarter partials into isub 0
#pragma unroll
    for (int src = 1; src < 4; ++src) {
        if (isub == src) {
#pragma unroll
            for (int jf = 0; jf < 2; ++jf)
#pragma unroll
                for (int cf = 0; cf < 4; ++cf)
#pragma unroll
                    for (int r = 0; r < 16; ++r) {
                        int jrow = (r & 3) + 8 * (r >> 2) + 4 * hi;
                        red[wc][jf * 32 + jrow][cf * 32 + lr] = acc[jf][cf][r];
                    }
        }
        __syncthreads();
        if (isub == 0) {
#pragma unroll
            for (int jf = 0; jf < 2; ++jf)
#pragma unroll
                for (int cf = 0; cf < 4; ++cf)
#pragma unroll
                    for (int r = 0; r < 16; ++r) {
                        int jrow = (r & 3) + 8 * (r >> 2) + 4 * hi;
                        acc[jf][cf][r] += red[wc][jf * 32 + jrow][cf * 32 + lr];
                    }
        }
        __syncthreads();
    }
    if (isub == 0) {
        const float gamma = *gammaPtr;
#pragma unroll
        for (int jf = 0; jf < 2; ++jf)
#pragma unroll
            for (int cf = 0; cf < 4; ++cf)
#pragma unroll
                for (int r = 0; r < 16; ++r) {
                    int jrow = (r & 3) + 8 * (r >> 2) + 4 * hi;
                    int j = j0 + jf * 32 + jrow;
                    size_t idx = (size_t)(b * 4096 + j) * 256 + c0 + cf * 32 + lr;
                    out[idx] = gamma * acc[jf][cf][r] + x[idx];
                }
    }
}

extern "C" void kernel_launch(void* const* d_in, const int* in_sizes, int n_in,
                              void* d_out, int out_size, void* d_ws, size_t ws_size,
                              hipStream_t stream)
{
    const float* x  = (const float*)d_in[0];
    const float* Wq = (const float*)d_in[1];
    const float* bq = (const float*)d_in[2];
    const float* Wk = (const float*)d_in[3];
    const float* bk = (const float*)d_in[4];
    const float* Wv = (const float*)d_in[5];
    const float* bv = (const float*)d_in[6];
    const float* gm = (const float*)d_in[7];
    float* out = (float*)d_out;

    char* wsb = (char*)d_ws;
    short* qf    = (short*)(wsb);
    short* kf    = (short*)(wsb + (1u << 20));
    short* vf    = (short*)(wsb + (2u << 20));
    short* wallF = (short*)(wsb + (10u << 20));
    float* ball  = (float*)(wsb + (10u << 20) + 163840);
    float* zpart = (float*)(wsb + (10u << 20) + 163840 + 1280);
    float* rz    = (float*)(wsb + (10u << 20) + 163840 + 1280 + 524288);

    pack_weights<<<320, 256, 0, stream>>>(Wq, Wk, Wv, bq, bk, bv, wallF, ball);
    qkv_gemm<<<1024, 256, 0, stream>>>(x, wallF, ball, qf, kf, vf);
    zsum_kernel<<<dim3(64, 4), 512, 0, stream>>>(qf, kf, zpart);
    zfinish<<<64, 256, 0, stream>>>(zpart, rz);
    vscale<<<2048, 256, 0, stream>>>(vf, rz);
    attn_out<<<256, 512, 0, stream>>>(qf, kf, vf, x, gm, out);
}

// Round 14
// 94.184 us; speedup vs baseline: 5.8751x; 1.0480x over previous
//
#include <hip/hip_runtime.h>
#include <hip/hip_bf16.h>

// B=4, H=W=64 -> N=4096, C=256, d=32
// All MFMA operands stored FRAGMENT-ORDERED so every load is a coalesced
// 1KB wave-load (lane-contiguous base + l*8 shorts).
//
// qF/kF [b][i>>5][f][lane][8] : lane = (i&31)+32*((d>>3)&1), f = d>>4, e = d&7
// vF    [b][i>>4][c>>5][lane][8] : lane = (c&31)+32*((i>>3)&1), e = i&7
// wallF [nf][ks][lane][8] : 16x16x32 B-frags of packed W^T (q|k|v)
// K (and bk) are pre-scaled by log2(e) so softmax uses v_exp_f32 (2^x) directly.
//
// NUMERICS GUARANTEE (R11 lesson): every exp2 input is clamped to <= 86.
// fminf also launders any non-finite S to 86. This bounds p <= 2^86,
// Z <= 2^98, and every P*vs term <= |v| -> acc provably finite. DO NOT REMOVE.
//
// ws layout (bytes):
//   qF    @ 0          1 MB
//   kF    @ 1 MB       1 MB
//   vF    @ 2 MB       8 MB
//   wallF @ 10 MB      160 KB
//   ball  @ +163840    1.25 KB
//   zpart @ +1280      512 KB   [8][16384] f32
//   rz    @ +524288    64 KB

typedef __attribute__((ext_vector_type(4)))  float    f32x4;
typedef __attribute__((ext_vector_type(16))) float    f32x16;
typedef __attribute__((ext_vector_type(8)))  short    bf8;
typedef __attribute__((ext_vector_type(4)))  short    bf4;
typedef __attribute__((ext_vector_type(4)))  unsigned u32x4;

__device__ __forceinline__ short f2bf(float f) {
    unsigned u = __builtin_bit_cast(unsigned, f);
    u += 0x7FFF + ((u >> 16) & 1);           // RNE
    return (short)(u >> 16);
}
__device__ __forceinline__ float bf2f(short h) {
    unsigned u = ((unsigned)(unsigned short)h) << 16;
    return __builtin_bit_cast(float, u);
}
__device__ __forceinline__ unsigned cvtpk(float lo, float hi) {
    unsigned r;
    asm("v_cvt_pk_bf16_f32 %0, %1, %2" : "=v"(r) : "v"(lo), "v"(hi));
    return r;
}
__device__ __forceinline__ float exp2_fast(float x) {   // 2^x, one v_exp_f32
    float r;
    asm("v_exp_f32 %0, %1" : "=v"(r) : "v"(x));
    return r;
}
__device__ __forceinline__ f32x16 z16() {
    f32x16 v;
#pragma unroll
    for (int i = 0; i < 16; ++i) v[i] = 0.f;
    return v;
}

#define LOG2E 1.44269504088896340736f

// ---------------- K1: pack weights into 16x16x32 B-frag order ---------------
__global__ __launch_bounds__(256) void pack_weights(
    const float* __restrict__ Wq, const float* __restrict__ Wk,
    const float* __restrict__ Wv, const float* __restrict__ bq,
    const float* __restrict__ bk, const float* __restrict__ bv,
    short* __restrict__ wallF, float* __restrict__ ball)
{
    int n = blockIdx.x;        // 0..319
    int k = threadIdx.x;       // 0..255
    float w;
    if (n < 32)       w = Wq[k * 32 + n];
    else if (n < 64)  w = Wk[k * 32 + (n - 32)] * LOG2E;   // fold log2e into K
    else              w = Wv[k * 256 + (n - 64)];
    int nf = n >> 4, lcol = n & 15;
    int ks = k >> 5, lg = (k >> 3) & 3, e = k & 7;
    wallF[((size_t)(nf * 8 + ks) * 64 + lg * 16 + lcol) * 8 + e] = f2bf(w);
    if (k == 0) {
        float bias = (n < 32) ? bq[n] : (n < 64) ? bk[n - 32] * LOG2E : bv[n - 64];
        ball[n] = bias;
    }
}

// ---------------- K2: QKV projection -> fragment-ordered qF/kF/vF -----------
// Grid 1024 (m16 per block), 4 waves split nf 20 -> 5 each. x rows L1-shared.
__global__ __launch_bounds__(256) void qkv_gemm(
    const float* __restrict__ x, const short* __restrict__ wallF,
    const float* __restrict__ ball,
    short* __restrict__ qf, short* __restrict__ kf, short* __restrict__ vf)
{
    const int w  = threadIdx.x >> 6;
    const int l  = threadIdx.x & 63;
    const int lr = l & 15;             // A row / B col within fragment
    const int lg = l >> 4;             // k-group
    const int m0 = blockIdx.x * 16;

    f32x4 acc[5];
#pragma unroll
    for (int i = 0; i < 5; ++i) acc[i] = (f32x4){0.f, 0.f, 0.f, 0.f};

    const float* xrow = x + (size_t)(m0 + lr) * 256 + lg * 8;
    const short* wwb  = wallF + (size_t)w * 5 * 4096 + l * 8;

#pragma unroll
    for (int ks = 0; ks < 8; ++ks) {
        f32x4 a0 = *(const f32x4*)(xrow + ks * 32);
        f32x4 a1 = *(const f32x4*)(xrow + ks * 32 + 4);
        bf8 af;
#pragma unroll
        for (int t = 0; t < 4; ++t) { af[t] = f2bf(a0[t]); af[t + 4] = f2bf(a1[t]); }
        const short* wb = wwb + (size_t)ks * 512;
#pragma unroll
        for (int nf2 = 0; nf2 < 5; ++nf2) {
            bf8 bfr = *(const bf8*)(wb + (size_t)nf2 * 4096);
            acc[nf2] = __builtin_amdgcn_mfma_f32_16x16x32_bf16(af, bfr, acc[nf2], 0, 0, 0);
        }
    }

    const int b      = m0 >> 12;
    const int i_base = m0 + lg * 4;          // rows i_base..i_base+3
#pragma unroll
    for (int nf2 = 0; nf2 < 5; ++nf2) {
        int nf = w * 5 + nf2;
        int n = nf * 16 + lr;
        float bias = ball[n];
        if (nf < 4) {          // q (nf<2) / k: d = n & 31
            int d = n & 31;
            int f = (d >> 4) & 1, sub = (d >> 3) & 1, e = d & 7;
            short* dst = (nf < 2) ? qf : kf;
            size_t base = ((size_t)(b * 128 + (i_base >> 5)) * 2 + f) * 512 + 256 * sub + e;
#pragma unroll
            for (int r = 0; r < 4; ++r) {
                int i31 = (i_base + r) & 31;
                dst[base + (size_t)i31 * 8] = f2bf(acc[nf2][r] + bias);
            }
        } else {               // v: c = n - 64
            int c = n - 64;
            bf4 pv;
#pragma unroll
            for (int r = 0; r < 4; ++r) pv[r] = f2bf(acc[nf2][r] + bias);
            size_t addr = (size_t)(b * 256 + (i_base >> 4)) * 4096
                        + (size_t)(c >> 5) * 512
                        + (size_t)((c & 31) + 32 * ((i_base >> 3) & 1)) * 8
                        + (i_base & 7);
            *(bf4*)(vf + addr) = pv;
        }
    }
}

// ---------------- K3: Z_i = sum_j 2^(q_i . k_j), swapped operands ------------
__global__ __launch_bounds__(512) void zsum_kernel(
    const short* __restrict__ qF, const short* __restrict__ kF,
    float* __restrict__ zpart)
{
    const int l = threadIdx.x & 63, w = threadIdx.x >> 6;
    const int b = blockIdx.y;
    const int it0 = blockIdx.x * 2;          // 0,2,..,126

    const short* qpa = qF + (size_t)(b * 128 + it0) * 1024 + l * 8;
    bf8 qa0 = *(const bf8*)(qpa);
    bf8 qa1 = *(const bf8*)(qpa + 512);
    bf8 qb0 = *(const bf8*)(qpa + 1024);
    bf8 qb1 = *(const bf8*)(qpa + 1536);

    float zA = 0.f, zB = 0.f;
    const short* kbase = kF + (size_t)b * 131072 + (size_t)w * 16384 + l * 8;
    for (int jt = 0; jt < 16; ++jt) {
        const short* kp = kbase + jt * 1024;
        bf8 kA0 = *(const bf8*)(kp);
        bf8 kA1 = *(const bf8*)(kp + 512);
        f32x16 SA = z16(), SB = z16();
        SA = __builtin_amdgcn_mfma_f32_32x32x16_bf16(kA0, qa0, SA, 0, 0, 0);
        SA = __builtin_amdgcn_mfma_f32_32x32x16_bf16(kA1, qa1, SA, 0, 0, 0);
        SB = __builtin_amdgcn_mfma_f32_32x32x16_bf16(kA0, qb0, SB, 0, 0, 0);
        SB = __builtin_amdgcn_mfma_f32_32x32x16_bf16(kA1, qb1, SB, 0, 0, 0);
#pragma unroll
        for (int r = 0; r < 16; ++r) {
            zA += exp2_fast(fminf(SA[r], 86.f));   // clamp: finiteness guarantee
            zB += exp2_fast(fminf(SB[r], 86.f));
        }
    }
    zA += __shfl_xor(zA, 32);
    zB += __shfl_xor(zB, 32);
    if (l < 32) {
        zpart[(size_t)w * 16384 + b * 4096 + it0 * 32 + l]      = zA;
        zpart[(size_t)w * 16384 + b * 4096 + it0 * 32 + 32 + l] = zB;
    }
}

// ---------------- K3b: rz = 1 / sum(partials) --------------------------------
__global__ __launch_bounds__(256) void zfinish(
    const float* __restrict__ zpart, float* __restrict__ rz)
{
    int i = blockIdx.x * 256 + threadIdx.x;   // 0..16383
    float z = 0.f;
#pragma unroll
    for (int p = 0; p < 8; ++p) z += zpart[p * 16384 + i];
    rz[i] = 1.0f / z;
}

// ---------------- K4: vs = v / Z  (in place on vF) ---------------------------
__global__ __launch_bounds__(256) void vscale(
    short* __restrict__ vF, const float* __restrict__ rz)
{
    int t = blockIdx.x * 256 + threadIdx.x;      // 0..524287
    size_t base = (size_t)t * 8;
    int b   = (int)(base >> 20);
    int rem = (int)(base & 1048575);
    int it  = rem >> 12;
    int sub = (rem >> 8) & 1;                    // lane>>5
    int i0  = it * 16 + sub * 8;
    bf8 v = *(bf8*)(vF + base);
    const float* rzp = rz + b * 4096 + i0;
    f32x4 r0 = *(const f32x4*)(rzp);
    f32x4 r1 = *(const f32x4*)(rzp + 4);
#pragma unroll
    for (int e = 0; e < 4; ++e) {
        v[e]     = f2bf(bf2f(v[e])     * r0[e]);
        v[e + 4] = f2bf(bf2f(v[e + 4]) * r1[e]);
    }
    *(bf8*)(vF + base) = v;
}

// ---------------- K5: out = gamma * (P^T @ vs) + x ---------------------------
// CROSS-WAVE SOFTMAX SHARE (R13 lesson: exp/QK still dup 2x across wc waves,
// and the serial QK->exp->pack->PV chain exposes latency at 2 waves/SIMD).
// The two wc waves at the same isub compute IDENTICAL S/P (same j-tile, same
// i) — only their c-half differs. So wave wc computes ONLY jf=wc's softmax
// (2 QK MFMA + 16 exp, was 4 + 32), publishes PA frags to LDS (lane-major
// 16B layout, conflict-free; double-buffered, ONE barrier/step); both waves
// read both jf. Loop is software-pipelined: softmax(t+1) issues BEFORE PV(t)
// so exp/pack (VALU+trans) overlap the 16 PV MFMAs within the wave.
// Grid 256 = 8 XCD x 32 (1 block/CU): b = xcd>>1, jt = (xcd&1)*32 + k.
// Block 512 = 8 waves = (2 wc) x (4 isub, stride-4 over 128 i-tiles).
// Epilogue: 3-round LDS reduce over isub (red aliases nothing; 96 KB total).
__global__ __launch_bounds__(512) void attn_out(
    const short* __restrict__ qF, const short* __restrict__ kF,
    const short* __restrict__ vF,
    const float* __restrict__ x, const float* __restrict__ gammaPtr,
    float* __restrict__ out)
{
    __shared__ short Pb[2][4][2][2][64][8];      // 32 KB [buf][isub][jf][frag][lane][8]
    __shared__ float red[2][64][128];            // 64 KB, epilogue only
    const int l = threadIdx.x & 63, w = threadIdx.x >> 6;
    const int lr = l & 31, hi = l >> 5;
    const int wc = w & 1, isub = w >> 1;         // wc = own jf; isub 0..3

    const int xcd = blockIdx.x & 7, k = blockIdx.x >> 3;    // k 0..31
    const int b = xcd >> 1;
    const int jt = (xcd & 1) * 32 + k;           // 0..63, j-tile of 64
    const int j0 = jt * 64;
    const int c0 = wc * 128;

    // K frags for OWN jf only (16 VGPR)
    const short* kfp = kF + (size_t)(b * 128 + jt * 2 + wc) * 1024 + l * 8;
    bf8 kf0 = *(const bf8*)(kfp);
    bf8 kf1 = *(const bf8*)(kfp + 512);

    f32x16 acc[2][4];
#pragma unroll
    for (int jf = 0; jf < 2; ++jf)
#pragma unroll
        for (int cf = 0; cf < 4; ++cf) acc[jf][cf] = z16();

    const short* qbase = qF + (size_t)b * 131072 + l * 8;
    const short* vbase = vF + (size_t)b * 1048576 + (size_t)(c0 >> 5) * 512 + l * 8;

    short* myP0 = &Pb[0][isub][wc][0][l][0];
    short* myP1 = &Pb[0][isub][wc][1][l][0];
    const size_t PbHalf = sizeof(short) * 4 * 2 * 2 * 64 * 8 / sizeof(short); // elems per buf

    // ---- prologue: softmax(0) -> LDS buf0; preload V first-quad(0)
    {
        bf8 q0 = *(const bf8*)(qbase + (size_t)isub * 1024);
        bf8 q1 = *(const bf8*)(qbase + (size_t)isub * 1024 + 512);
        f32x16 S = z16();
        S = __builtin_amdgcn_mfma_f32_32x32x16_bf16(q0, kf0, S, 0, 0, 0);
        S = __builtin_amdgcn_mfma_f32_32x32x16_bf16(q1, kf1, S, 0, 0, 0);
        float p[16];
#pragma unroll
        for (int r = 0; r < 16; ++r) p[r] = exp2_fast(fminf(S[r], 86.f));
        unsigned X0 = cvtpk(p[0],  p[1]),  Y0 = cvtpk(p[4],  p[5]);
        unsigned X1 = cvtpk(p[2],  p[3]),  Y1 = cvtpk(p[6],  p[7]);
        unsigned X2 = cvtpk(p[8],  p[9]),  Y2 = cvtpk(p[12], p[13]);
        unsigned X3 = cvtpk(p[10], p[11]), Y3 = cvtpk(p[14], p[15]);
        asm("v_permlane32_swap_b32 %0, %1" : "+v"(X0), "+v"(Y0));
        asm("v_permlane32_swap_b32 %0, %1" : "+v"(X1), "+v"(Y1));
        asm("v_permlane32_swap_b32 %0, %1" : "+v"(X2), "+v"(Y2));
        asm("v_permlane32_swap_b32 %0, %1" : "+v"(X3), "+v"(Y3));
        u32x4 a0w = {X0, X1, Y0, Y1};
        u32x4 a1w = {X2, X3, Y2, Y3};
        *(bf8*)myP0 = __builtin_bit_cast(bf8, a0w);
        *(bf8*)myP1 = __builtin_bit_cast(bf8, a1w);
    }
    bf8 v0[4];
#pragma unroll
    for (int cf = 0; cf < 4; ++cf)
        v0[cf] = *(const bf8*)(vbase + (size_t)isub * 8192 + cf * 512);

    for (int t = 0; t < 32; ++t) {
        __syncthreads();                          // P(t) visible in buf[t&1]
        const int m = isub + t * 4;
        // read both jf's PA frags for step t
        const short* pb = &Pb[t & 1][isub][0][0][l][0];
        bf8 pa00 = *(const bf8*)(pb);             // jf0 frag0
        bf8 pa01 = *(const bf8*)(pb + 512);       // jf0 frag1
        bf8 pa10 = *(const bf8*)(pb + 1024);      // jf1 frag0
        bf8 pa11 = *(const bf8*)(pb + 1536);      // jf1 frag1

        // issue loads: second V quad (t), first V quad (t+1), q(t+1)
        const short* vp = vbase + (size_t)m * 8192;
        bf8 cv1[4];
#pragma unroll
        for (int cf = 0; cf < 4; ++cf)
            cv1[cf] = *(const bf8*)(vp + 4096 + cf * 512);
        bf8 nv0[4];
#pragma unroll
        for (int cf = 0; cf < 4; ++cf) nv0[cf] = v0[cf];
        if (t < 31) {
            const short* vn = vbase + (size_t)(m + 4) * 8192;
#pragma unroll
            for (int cf = 0; cf < 4; ++cf)
                nv0[cf] = *(const bf8*)(vn + cf * 512);
            // ---- softmax(t+1) for own jf, write to buf[(t+1)&1]
            const short* qn = qbase + (size_t)(m + 4) * 1024;
            bf8 q0 = *(const bf8*)(qn);
            bf8 q1 = *(const bf8*)(qn + 512);
            f32x16 S = z16();
            S = __builtin_amdgcn_mfma_f32_32x32x16_bf16(q0, kf0, S, 0, 0, 0);
            S = __builtin_amdgcn_mfma_f32_32x32x16_bf16(q1, kf1, S, 0, 0, 0);
            float p[16];
#pragma unroll
            for (int r = 0; r < 16; ++r) p[r] = exp2_fast(fminf(S[r], 86.f));
            unsigned X0 = cvtpk(p[0],  p[1]),  Y0 = cvtpk(p[4],  p[5]);
            unsigned X1 = cvtpk(p[2],  p[3]),  Y1 = cvtpk(p[6],  p[7]);
            unsigned X2 = cvtpk(p[8],  p[9]),  Y2 = cvtpk(p[12], p[13]);
            unsigned X3 = cvtpk(p[10], p[11]), Y3 = cvtpk(p[14], p[15]);
            asm("v_permlane32_swap_b32 %0, %1" : "+v"(X0), "+v"(Y0));
            asm("v_permlane32_swap_b32 %0, %1" : "+v"(X1), "+v"(Y1));
            asm("v_permlane32_swap_b32 %0, %1" : "+v"(X2), "+v"(Y2));
            asm("v_permlane32_swap_b32 %0, %1" : "+v"(X3), "+v"(Y3));
            u32x4 a0w = {X0, X1, Y0, Y1};
            u32x4 a1w = {X2, X3, Y2, Y3};
            short* dst = myP0 + ((t + 1) & 1) * PbHalf;
            *(bf8*)(dst)       = __builtin_bit_cast(bf8, a0w);
            *(bf8*)(dst + 512) = __builtin_bit_cast(bf8, a1w);
        }

        // ---- PV(t): 16 MFMA, overlaps the softmax VALU above
        __builtin_amdgcn_s_setprio(1);
#pragma unroll
        for (int cf = 0; cf < 4; ++cf) {
            acc[0][cf] = __builtin_amdgcn_mfma_f32_32x32x16_bf16(pa00, v0[cf],  acc[0][cf], 0, 0, 0);
            acc[0][cf] = __builtin_amdgcn_mfma_f32_32x32x16_bf16(pa01, cv1[cf], acc[0][cf], 0, 0, 0);
            acc[1][cf] = __builtin_amdgcn_mfma_f32_32x32x16_bf16(pa10, v0[cf],  acc[1][cf], 0, 0, 0);
            acc[1][cf] = __builtin_amdgcn_mfma_f32_32x32x16_bf16(pa11, cv1[cf], acc[1][cf], 0, 0, 0);
        }
        __builtin_amdgcn_s_setprio(0);

#pragma unroll
        for (int cf = 0; cf < 4; ++cf) v0[cf] = nv0[cf];
    }

    // epilogue: 3-round reduce of the 4 i-quarter partials into isub 0
#pragma unroll
    for (int src = 1; src < 4; ++src) {
        if (isub == src) {
#pragma unroll
            for (int jf = 0; jf < 2; ++jf)
#pragma unroll
                for (int cf = 0; cf < 4; ++cf)
#pragma unroll
                    for (int r = 0; r < 16; ++r) {
                        int jrow = (r & 3) + 8 * (r >> 2) + 4 * hi;
                        red[wc][jf * 32 + jrow][cf * 32 + lr] = acc[jf][cf][r];
                    }
        }
        __syncthreads();
        if (isub == 0) {
#pragma unroll
            for (int jf = 0; jf < 2; ++jf)
#pragma unroll
                for (int cf = 0; cf < 4; ++cf)
#pragma unroll
                    for (int r = 0; r < 16; ++r) {
                        int jrow = (r & 3) + 8 * (r >> 2) + 4 * hi;
                        acc[jf][cf][r] += red[wc][jf * 32 + jrow][cf * 32 + lr];
                    }
        }
        __syncthreads();
    }
    if (isub == 0) {
        const float gamma = *gammaPtr;
#pragma unroll
        for (int jf = 0; jf < 2; ++jf)
#pragma unroll
            for (int cf = 0; cf < 4; ++cf)
#pragma unroll
                for (int r = 0; r < 16; ++r) {
                    int jrow = (r & 3) + 8 * (r >> 2) + 4 * hi;
                    int j = j0 + jf * 32 + jrow;
                    size_t idx = (size_t)(b * 4096 + j) * 256 + c0 + cf * 32 + lr;
                    out[idx] = gamma * acc[jf][cf][r] + x[idx];
                }
    }
}

extern "C" void kernel_launch(void* const* d_in, const int* in_sizes, int n_in,
                              void* d_out, int out_size, void* d_ws, size_t ws_size,
                              hipStream_t stream)
{
    const float* x  = (const float*)d_in[0];
    const float* Wq = (const float*)d_in[1];
    const float* bq = (const float*)d_in[2];
    const float* Wk = (const float*)d_in[3];
    const float* bk = (const float*)d_in[4];
    const float* Wv = (const float*)d_in[5];
    const float* bv = (const float*)d_in[6];
    const float* gm = (const float*)d_in[7];
    float* out = (float*)d_out;

    char* wsb = (char*)d_ws;
    short* qf    = (short*)(wsb);
    short* kf    = (short*)(wsb + (1u << 20));
    short* vf    = (short*)(wsb + (2u << 20));
    short* wallF = (short*)(wsb + (10u << 20));
    float* ball  = (float*)(wsb + (10u << 20) + 163840);
    float* zpart = (float*)(wsb + (10u << 20) + 163840 + 1280);
    float* rz    = (float*)(wsb + (10u << 20) + 163840 + 1280 + 524288);

    pack_weights<<<320, 256, 0, stream>>>(Wq, Wk, Wv, bq, bk, bv, wallF, ball);
    qkv_gemm<<<1024, 256, 0, stream>>>(x, wallF, ball, qf, kf, vf);
    zsum_kernel<<<dim3(64, 4), 512, 0, stream>>>(qf, kf, zpart);
    zfinish<<<64, 256, 0, stream>>>(zpart, rz);
    vscale<<<2048, 256, 0, stream>>>(vf, rz);
    attn_out<<<256, 512, 0, stream>>>(qf, kf, vf, x, gm, out);
}

// Round 15
// 90.904 us; speedup vs baseline: 6.0871x; 1.0361x over previous
//
#include <hip/hip_runtime.h>
#include <hip/hip_bf16.h>

// B=4, H=W=64 -> N=4096, C=256, d=32
// All MFMA operands stored FRAGMENT-ORDERED so every load is a coalesced
// 1KB wave-load (lane-contiguous base + l*8 shorts).
//
// qF/kF [b][i>>5][f][lane][8] : lane = (i&31)+32*((d>>3)&1), f = d>>4, e = d&7
// vF    [b][i>>4][c>>5][lane][8] : lane = (c&31)+32*((i>>3)&1), e = i&7
// wallF [nf][ks][lane][8] : 16x16x32 B-frags of packed W^T (q|k|v)
// K (and bk) pre-scaled by log2(e): softmax uses v_exp_f32 (2^x) directly.
// 1/Z is folded into softmax via lrz = -log2(Z): p = 2^(S + lrz_i) <= 1.
//
// NUMERICS GUARANTEE (R11 lesson): every exp2 input is clamped to <= 86.
// fminf also launders any non-finite input to 86. This bounds p and keeps
// acc provably finite. Removing the clamp produced NaN (0*inf). DO NOT REMOVE.
//
// BARRIER DISCIPLINE (R14 lesson): __syncthreads() in the main loop emits
// s_waitcnt vmcnt(0) before s_barrier, draining the V/q prefetch every step.
// The loop uses raw s_barrier with an lgkmcnt(0)-only producer fence so
// global prefetch stays in flight across the barrier.
//
// ws layout (bytes):
//   qF    @ 0          1 MB
//   kF    @ 1 MB       1 MB
//   vF    @ 2 MB       8 MB
//   wallF @ 10 MB      160 KB
//   ball  @ +163840    1.25 KB
//   zpart @ +1280      512 KB   [8][16384] f32
//   lrz   @ +524288    64 KB    -log2(Z)

typedef __attribute__((ext_vector_type(4)))  float    f32x4;
typedef __attribute__((ext_vector_type(16))) float    f32x16;
typedef __attribute__((ext_vector_type(8)))  short    bf8;
typedef __attribute__((ext_vector_type(4)))  short    bf4;
typedef __attribute__((ext_vector_type(4)))  unsigned u32x4;

__device__ __forceinline__ short f2bf(float f) {
    unsigned u = __builtin_bit_cast(unsigned, f);
    u += 0x7FFF + ((u >> 16) & 1);           // RNE
    return (short)(u >> 16);
}
__device__ __forceinline__ unsigned cvtpk(float lo, float hi) {
    unsigned r;
    asm("v_cvt_pk_bf16_f32 %0, %1, %2" : "=v"(r) : "v"(lo), "v"(hi));
    return r;
}
__device__ __forceinline__ float exp2_fast(float x) {   // 2^x, one v_exp_f32
    float r;
    asm("v_exp_f32 %0, %1" : "=v"(r) : "v"(x));
    return r;
}
__device__ __forceinline__ f32x16 z16() {
    f32x16 v;
#pragma unroll
    for (int i = 0; i < 16; ++i) v[i] = 0.f;
    return v;
}

#define LOG2E 1.44269504088896340736f

// ---------------- K1: pack weights into 16x16x32 B-frag order ---------------
__global__ __launch_bounds__(256) void pack_weights(
    const float* __restrict__ Wq, const float* __restrict__ Wk,
    const float* __restrict__ Wv, const float* __restrict__ bq,
    const float* __restrict__ bk, const float* __restrict__ bv,
    short* __restrict__ wallF, float* __restrict__ ball)
{
    int n = blockIdx.x;        // 0..319
    int k = threadIdx.x;       // 0..255
    float w;
    if (n < 32)       w = Wq[k * 32 + n];
    else if (n < 64)  w = Wk[k * 32 + (n - 32)] * LOG2E;   // fold log2e into K
    else              w = Wv[k * 256 + (n - 64)];
    int nf = n >> 4, lcol = n & 15;
    int ks = k >> 5, lg = (k >> 3) & 3, e = k & 7;
    wallF[((size_t)(nf * 8 + ks) * 64 + lg * 16 + lcol) * 8 + e] = f2bf(w);
    if (k == 0) {
        float bias = (n < 32) ? bq[n] : (n < 64) ? bk[n - 32] * LOG2E : bv[n - 64];
        ball[n] = bias;
    }
}

// ---------------- K2: QKV projection -> fragment-ordered qF/kF/vF -----------
// Grid 256 (m64 per block), 4 waves x m16; each wave all 20 nf-frags.
// wallF loaded once per block (41 MB chip-wide, was 164 MB at grid 1024).
__global__ __launch_bounds__(256) void qkv_gemm(
    const float* __restrict__ x, const short* __restrict__ wallF,
    const float* __restrict__ ball,
    short* __restrict__ qf, short* __restrict__ kf, short* __restrict__ vf)
{
    const int w  = threadIdx.x >> 6;
    const int l  = threadIdx.x & 63;
    const int lr = l & 15;             // A row / B col within fragment
    const int lg = l >> 4;             // k-group
    const int m0 = blockIdx.x * 64 + w * 16;

    f32x4 acc[20];
#pragma unroll
    for (int i = 0; i < 20; ++i) acc[i] = (f32x4){0.f, 0.f, 0.f, 0.f};

    const float* xrow = x + (size_t)(m0 + lr) * 256 + lg * 8;

#pragma unroll
    for (int ks = 0; ks < 8; ++ks) {
        f32x4 a0 = *(const f32x4*)(xrow + ks * 32);
        f32x4 a1 = *(const f32x4*)(xrow + ks * 32 + 4);
        bf8 af;
#pragma unroll
        for (int t = 0; t < 4; ++t) { af[t] = f2bf(a0[t]); af[t + 4] = f2bf(a1[t]); }
        const short* wb = wallF + (size_t)ks * 512 + l * 8;
#pragma unroll
        for (int nf = 0; nf < 20; ++nf) {
            bf8 bfr = *(const bf8*)(wb + (size_t)nf * 4096);
            acc[nf] = __builtin_amdgcn_mfma_f32_16x16x32_bf16(af, bfr, acc[nf], 0, 0, 0);
        }
    }

    const int b      = m0 >> 12;
    const int i_base = m0 + lg * 4;          // rows i_base..i_base+3
#pragma unroll
    for (int nf = 0; nf < 20; ++nf) {
        int n = nf * 16 + lr;
        float bias = ball[n];
        if (nf < 4) {          // q (nf<2) / k: d = n & 31
            int d = n & 31;
            int f = (d >> 4) & 1, sub = (d >> 3) & 1, e = d & 7;
            short* dst = (nf < 2) ? qf : kf;
            size_t base = ((size_t)(b * 128 + (i_base >> 5)) * 2 + f) * 512 + 256 * sub + e;
#pragma unroll
            for (int r = 0; r < 4; ++r) {
                int i31 = (i_base + r) & 31;
                dst[base + (size_t)i31 * 8] = f2bf(acc[nf][r] + bias);
            }
        } else {               // v: c = n - 64
            int c = n - 64;
            bf4 pv;
#pragma unroll
            for (int r = 0; r < 4; ++r) pv[r] = f2bf(acc[nf][r] + bias);
            size_t addr = (size_t)(b * 256 + (i_base >> 4)) * 4096
                        + (size_t)(c >> 5) * 512
                        + (size_t)((c & 31) + 32 * ((i_base >> 3) & 1)) * 8
                        + (i_base & 7);
            *(bf4*)(vf + addr) = pv;
        }
    }
}

// ---------------- K3: Z_i = sum_j 2^(q_i . k_j), swapped operands ------------
__global__ __launch_bounds__(512) void zsum_kernel(
    const short* __restrict__ qF, const short* __restrict__ kF,
    float* __restrict__ zpart)
{
    const int l = threadIdx.x & 63, w = threadIdx.x >> 6;
    const int b = blockIdx.y;
    const int it0 = blockIdx.x * 2;          // 0,2,..,126

    const short* qpa = qF + (size_t)(b * 128 + it0) * 1024 + l * 8;
    bf8 qa0 = *(const bf8*)(qpa);
    bf8 qa1 = *(const bf8*)(qpa + 512);
    bf8 qb0 = *(const bf8*)(qpa + 1024);
    bf8 qb1 = *(const bf8*)(qpa + 1536);

    float zA = 0.f, zB = 0.f;
    const short* kbase = kF + (size_t)b * 131072 + (size_t)w * 16384 + l * 8;
    for (int jt = 0; jt < 16; ++jt) {
        const short* kp = kbase + jt * 1024;
        bf8 kA0 = *(const bf8*)(kp);
        bf8 kA1 = *(const bf8*)(kp + 512);
        f32x16 SA = z16(), SB = z16();
        SA = __builtin_amdgcn_mfma_f32_32x32x16_bf16(kA0, qa0, SA, 0, 0, 0);
        SA = __builtin_amdgcn_mfma_f32_32x32x16_bf16(kA1, qa1, SA, 0, 0, 0);
        SB = __builtin_amdgcn_mfma_f32_32x32x16_bf16(kA0, qb0, SB, 0, 0, 0);
        SB = __builtin_amdgcn_mfma_f32_32x32x16_bf16(kA1, qb1, SB, 0, 0, 0);
#pragma unroll
        for (int r = 0; r < 16; ++r) {
            zA += exp2_fast(fminf(SA[r], 86.f));   // clamp: finiteness guarantee
            zB += exp2_fast(fminf(SB[r], 86.f));
        }
    }
    zA += __shfl_xor(zA, 32);
    zB += __shfl_xor(zB, 32);
    if (l < 32) {
        zpart[(size_t)w * 16384 + b * 4096 + it0 * 32 + l]      = zA;
        zpart[(size_t)w * 16384 + b * 4096 + it0 * 32 + 32 + l] = zB;
    }
}

// ---------------- K3b: lrz = -log2(sum of partials) --------------------------
__global__ __launch_bounds__(256) void zfinish(
    const float* __restrict__ zpart, float* __restrict__ lrz)
{
    int i = blockIdx.x * 256 + threadIdx.x;   // 0..16383
    float z = 0.f;
#pragma unroll
    for (int p = 0; p < 8; ++p) z += zpart[p * 16384 + i];
    lrz[i] = -__log2f(z);
}

// ---------------- K5: out = gamma * (P^T @ V) + x ----------------------------
// Cross-wave softmax share (R14) + RAW-BARRIER loop (R15): wave wc computes
// only jf=wc's softmax (2 QK MFMA + 16 exp), publishes PA frags to LDS
// (double-buffered); both wc waves read both jf. 1/Z folded via lrz (vscale
// kernel deleted). Loop barrier = lgkmcnt(0) fence + raw s_barrier — NO
// vmcnt drain, so V/q prefetch survives the barrier.
// Grid 256 = 8 XCD x 32 (1 block/CU): b = xcd>>1, jt = (xcd&1)*32 + k.
// Block 512 = 8 waves = (2 wc) x (4 isub, stride-4 over 128 i-tiles).
// Epilogue: 3-round LDS reduce over isub (full __syncthreads, 6 total).
__global__ __launch_bounds__(512) void attn_out(
    const short* __restrict__ qF, const short* __restrict__ kF,
    const short* __restrict__ vF, const float* __restrict__ lrz,
    const float* __restrict__ x, const float* __restrict__ gammaPtr,
    float* __restrict__ out)
{
    __shared__ short Pb[2][4][2][2][64][8];      // 32 KB [buf][isub][jf][frag][lane][8]
    __shared__ float red[2][64][128];            // 64 KB, epilogue only
    const int l = threadIdx.x & 63, w = threadIdx.x >> 6;
    const int lr = l & 31, hi = l >> 5;
    const int wc = w & 1, isub = w >> 1;         // wc = own jf; isub 0..3

    const int xcd = blockIdx.x & 7, k = blockIdx.x >> 3;    // k 0..31
    const int b = xcd >> 1;
    const int jt = (xcd & 1) * 32 + k;           // 0..63, j-tile of 64
    const int j0 = jt * 64;
    const int c0 = wc * 128;

    // K frags for OWN jf only (16 VGPR)
    const short* kfp = kF + (size_t)(b * 128 + jt * 2 + wc) * 1024 + l * 8;
    bf8 kf0 = *(const bf8*)(kfp);
    bf8 kf1 = *(const bf8*)(kfp + 512);

    f32x16 acc[2][4];
#pragma unroll
    for (int jf = 0; jf < 2; ++jf)
#pragma unroll
        for (int cf = 0; cf < 4; ++cf) acc[jf][cf] = z16();

    const short* qbase = qF + (size_t)b * 131072 + l * 8;
    const short* vbase = vF + (size_t)b * 1048576 + (size_t)(c0 >> 5) * 512 + l * 8;
    const float* lzb   = lrz + b * 4096 + 4 * hi;

    short* myP0 = &Pb[0][isub][wc][0][l][0];
    short* myP1 = &Pb[0][isub][wc][1][l][0];
    const int PbHalf = 4 * 2 * 2 * 64 * 8;       // shorts per buffer

    // ---- prologue: softmax(0) -> LDS buf0; preload V first-quad(0)
    {
        bf8 q0 = *(const bf8*)(qbase + (size_t)isub * 1024);
        bf8 q1 = *(const bf8*)(qbase + (size_t)isub * 1024 + 512);
        const float* lzt = lzb + isub * 32;
        f32x4 lz0 = *(const f32x4*)(lzt);
        f32x4 lz1 = *(const f32x4*)(lzt + 8);
        f32x4 lz2 = *(const f32x4*)(lzt + 16);
        f32x4 lz3 = *(const f32x4*)(lzt + 24);
        f32x16 S = z16();
        S = __builtin_amdgcn_mfma_f32_32x32x16_bf16(q0, kf0, S, 0, 0, 0);
        S = __builtin_amdgcn_mfma_f32_32x32x16_bf16(q1, kf1, S, 0, 0, 0);
        float p[16];
#pragma unroll
        for (int r = 0; r < 16; ++r) {
            float lz = (r < 4) ? lz0[r & 3] : (r < 8) ? lz1[r & 3]
                     : (r < 12) ? lz2[r & 3] : lz3[r & 3];
            p[r] = exp2_fast(fminf(S[r] + lz, 86.f));
        }
        unsigned X0 = cvtpk(p[0],  p[1]),  Y0 = cvtpk(p[4],  p[5]);
        unsigned X1 = cvtpk(p[2],  p[3]),  Y1 = cvtpk(p[6],  p[7]);
        unsigned X2 = cvtpk(p[8],  p[9]),  Y2 = cvtpk(p[12], p[13]);
        unsigned X3 = cvtpk(p[10], p[11]), Y3 = cvtpk(p[14], p[15]);
        asm("v_permlane32_swap_b32 %0, %1" : "+v"(X0), "+v"(Y0));
        asm("v_permlane32_swap_b32 %0, %1" : "+v"(X1), "+v"(Y1));
        asm("v_permlane32_swap_b32 %0, %1" : "+v"(X2), "+v"(Y2));
        asm("v_permlane32_swap_b32 %0, %1" : "+v"(X3), "+v"(Y3));
        u32x4 a0w = {X0, X1, Y0, Y1};
        u32x4 a1w = {X2, X3, Y2, Y3};
        *(bf8*)myP0 = __builtin_bit_cast(bf8, a0w);
        *(bf8*)myP1 = __builtin_bit_cast(bf8, a1w);
    }
    bf8 v0[4];
#pragma unroll
    for (int cf = 0; cf < 4; ++cf)
        v0[cf] = *(const bf8*)(vbase + (size_t)isub * 8192 + cf * 512);

    for (int t = 0; t < 32; ++t) {
        // RAW barrier: drain LDS writes only — vmcnt (global prefetch) stays live
        asm volatile("s_waitcnt lgkmcnt(0)" ::: "memory");
        __builtin_amdgcn_s_barrier();
        asm volatile("" ::: "memory");

        const int m = isub + t * 4;
        // read both jf's PA frags for step t
        const short* pb = &Pb[t & 1][isub][0][0][l][0];
        bf8 pa00 = *(const bf8*)(pb);             // jf0 frag0
        bf8 pa01 = *(const bf8*)(pb + 512);       // jf0 frag1
        bf8 pa10 = *(const bf8*)(pb + 1024);      // jf1 frag0
        bf8 pa11 = *(const bf8*)(pb + 1536);      // jf1 frag1

        // issue loads: second V quad (t), first V quad (t+1)
        const short* vp = vbase + (size_t)m * 8192;
        bf8 cv1[4];
#pragma unroll
        for (int cf = 0; cf < 4; ++cf)
            cv1[cf] = *(const bf8*)(vp + 4096 + cf * 512);
        bf8 nv0[4];
#pragma unroll
        for (int cf = 0; cf < 4; ++cf) nv0[cf] = v0[cf];
        if (t < 31) {
            const short* vn = vbase + (size_t)(m + 4) * 8192;
#pragma unroll
            for (int cf = 0; cf < 4; ++cf)
                nv0[cf] = *(const bf8*)(vn + cf * 512);
            // ---- softmax(t+1) for own jf, write to buf[(t+1)&1]
            const short* qn = qbase + (size_t)(m + 4) * 1024;
            bf8 q0 = *(const bf8*)(qn);
            bf8 q1 = *(const bf8*)(qn + 512);
            const float* lzt = lzb + (m + 4) * 32;
            f32x4 lz0 = *(const f32x4*)(lzt);
            f32x4 lz1 = *(const f32x4*)(lzt + 8);
            f32x4 lz2 = *(const f32x4*)(lzt + 16);
            f32x4 lz3 = *(const f32x4*)(lzt + 24);
            f32x16 S = z16();
            S = __builtin_amdgcn_mfma_f32_32x32x16_bf16(q0, kf0, S, 0, 0, 0);
            S = __builtin_amdgcn_mfma_f32_32x32x16_bf16(q1, kf1, S, 0, 0, 0);
            float p[16];
#pragma unroll
            for (int r = 0; r < 16; ++r) {
                float lz = (r < 4) ? lz0[r & 3] : (r < 8) ? lz1[r & 3]
                         : (r < 12) ? lz2[r & 3] : lz3[r & 3];
                p[r] = exp2_fast(fminf(S[r] + lz, 86.f));
            }
            unsigned X0 = cvtpk(p[0],  p[1]),  Y0 = cvtpk(p[4],  p[5]);
            unsigned X1 = cvtpk(p[2],  p[3]),  Y1 = cvtpk(p[6],  p[7]);
            unsigned X2 = cvtpk(p[8],  p[9]),  Y2 = cvtpk(p[12], p[13]);
            unsigned X3 = cvtpk(p[10], p[11]), Y3 = cvtpk(p[14], p[15]);
            asm("v_permlane32_swap_b32 %0, %1" : "+v"(X0), "+v"(Y0));
            asm("v_permlane32_swap_b32 %0, %1" : "+v"(X1), "+v"(Y1));
            asm("v_permlane32_swap_b32 %0, %1" : "+v"(X2), "+v"(Y2));
            asm("v_permlane32_swap_b32 %0, %1" : "+v"(X3), "+v"(Y3));
            u32x4 a0w = {X0, X1, Y0, Y1};
            u32x4 a1w = {X2, X3, Y2, Y3};
            short* dst = myP0 + ((t + 1) & 1) * PbHalf;
            *(bf8*)(dst)       = __builtin_bit_cast(bf8, a0w);
            *(bf8*)(dst + 512) = __builtin_bit_cast(bf8, a1w);
        }

        // ---- PV(t): 16 MFMA, overlaps the softmax VALU above
        __builtin_amdgcn_s_setprio(1);
#pragma unroll
        for (int cf = 0; cf < 4; ++cf) {
            acc[0][cf] = __builtin_amdgcn_mfma_f32_32x32x16_bf16(pa00, v0[cf],  acc[0][cf], 0, 0, 0);
            acc[0][cf] = __builtin_amdgcn_mfma_f32_32x32x16_bf16(pa01, cv1[cf], acc[0][cf], 0, 0, 0);
            acc[1][cf] = __builtin_amdgcn_mfma_f32_32x32x16_bf16(pa10, v0[cf],  acc[1][cf], 0, 0, 0);
            acc[1][cf] = __builtin_amdgcn_mfma_f32_32x32x16_bf16(pa11, cv1[cf], acc[1][cf], 0, 0, 0);
        }
        __builtin_amdgcn_s_setprio(0);

#pragma unroll
        for (int cf = 0; cf < 4; ++cf) v0[cf] = nv0[cf];
    }

    // epilogue: 3-round reduce of the 4 i-quarter partials into isub 0
#pragma unroll
    for (int src = 1; src < 4; ++src) {
        if (isub == src) {
#pragma unroll
            for (int jf = 0; jf < 2; ++jf)
#pragma unroll
                for (int cf = 0; cf < 4; ++cf)
#pragma unroll
                    for (int r = 0; r < 16; ++r) {
                        int jrow = (r & 3) + 8 * (r >> 2) + 4 * hi;
                        red[wc][jf * 32 + jrow][cf * 32 + lr] = acc[jf][cf][r];
                    }
        }
        __syncthreads();
        if (isub == 0) {
#pragma unroll
            for (int jf = 0; jf < 2; ++jf)
#pragma unroll
                for (int cf = 0; cf < 4; ++cf)
#pragma unroll
                    for (int r = 0; r < 16; ++r) {
                        int jrow = (r & 3) + 8 * (r >> 2) + 4 * hi;
                        acc[jf][cf][r] += red[wc][jf * 32 + jrow][cf * 32 + lr];
                    }
        }
        __syncthreads();
    }
    if (isub == 0) {
        const float gamma = *gammaPtr;
#pragma unroll
        for (int jf = 0; jf < 2; ++jf)
#pragma unroll
            for (int cf = 0; cf < 4; ++cf)
#pragma unroll
                for (int r = 0; r < 16; ++r) {
                    int jrow = (r & 3) + 8 * (r >> 2) + 4 * hi;
                    int j = j0 + jf * 32 + jrow;
                    size_t idx = (size_t)(b * 4096 + j) * 256 + c0 + cf * 32 + lr;
                    out[idx] = gamma * acc[jf][cf][r] + x[idx];
                }
    }
}

extern "C" void kernel_launch(void* const* d_in, const int* in_sizes, int n_in,
                              void* d_out, int out_size, void* d_ws, size_t ws_size,
                              hipStream_t stream)
{
    const float* x  = (const float*)d_in[0];
    const float* Wq = (const float*)d_in[1];
    const float* bq = (const float*)d_in[2];
    const float* Wk = (const float*)d_in[3];
    const float* bk = (const float*)d_in[4];
    const float* Wv = (const float*)d_in[5];
    const float* bv = (const float*)d_in[6];
    const float* gm = (const float*)d_in[7];
    float* out = (float*)d_out;

    char* wsb = (char*)d_ws;
    short* qf    = (short*)(wsb);
    short* kf    = (short*)(wsb + (1u << 20));
    short* vf    = (short*)(wsb + (2u << 20));
    short* wallF = (short*)(wsb + (10u << 20));
    float* ball  = (float*)(wsb + (10u << 20) + 163840);
    float* zpart = (float*)(wsb + (10u << 20) + 163840 + 1280);
    float* lrz   = (float*)(wsb + (10u << 20) + 163840 + 1280 + 524288);

    pack_weights<<<320, 256, 0, stream>>>(Wq, Wk, Wv, bq, bk, bv, wallF, ball);
    qkv_gemm<<<256, 256, 0, stream>>>(x, wallF, ball, qf, kf, vf);
    zsum_kernel<<<dim3(64, 4), 512, 0, stream>>>(qf, kf, zpart);
    zfinish<<<64, 256, 0, stream>>>(zpart, lrz);
    attn_out<<<256, 512, 0, stream>>>(qf, kf, vf, lrz, x, gm, out);
}